// Round 2
// baseline (1409.586 us; speedup 1.0000x reference)
//
#include <hip/hip_runtime.h>
#include <cstdint>
#include <cstddef>
#include <math.h>

// Problem dims
#define NB    16
#define SS    4096
#define DIN   64
#define DK    512
#define DIEXP 768
#define MROWS (NB*SS)      // 65536
#define NHG   (2*DIEXP)    // 1536
#define CCH   32           // chunks per sequence (chunk len = 128 rows/block)
#define TCH   (SS/CCH)     // 128
#define NCHAN (NB*DIEXP)   // 12288

__device__ __forceinline__ float lax(float P, float L, float V) {
  // logaddexp(P + L, V); L may be -inf, P/V finite
  float xx = P + L;
  float m  = fmaxf(xx, V);
  float d  = fminf(xx, V) - m;     // <= 0; -inf ok (exp -> 0)
  return m + __logf(1.f + __expf(d));
}

__device__ __forceinline__ void gate_math(float g, float h, float& lcv, float& lvv) {
  float spg  = fmaxf(g, 0.f) + __logf(1.f + __expf(-fabsf(g)));   // softplus(g)
  float logg = (h >= 0.f) ? __logf(h + 0.5f)
                          : (h - __logf(1.f + __expf(h)));        // log g(h)
  lcv = -spg;              // log(1-z)
  lvv = g - spg + logg;    // log z + log g(h)
}

// ---------------------------------------------------------------------------
// K1 (path A): x = obs @ W_emb + b_emb
// ---------------------------------------------------------------------------
__global__ __launch_bounds__(256) void emb_gemm(
    const float* __restrict__ obs, const float* __restrict__ Wemb,
    const float* __restrict__ bemb, float* __restrict__ x)
{
  __shared__ float As[16][132];
  __shared__ float Bs[16][64];
  const int tid = threadIdx.x;
  const int tr = tid >> 4, tc = tid & 15;
  const int row0 = blockIdx.x * 128;
  const int col0 = blockIdx.y * 64;
  float acc[8][4] = {};

  for (int kt = 0; kt < DIN/16; ++kt) {
    float4 av[2];
#pragma unroll
    for (int r = 0; r < 2; ++r) {
      int idx = tid + 256*r;
      int m = idx >> 2, k4 = idx & 3;
      av[r] = *reinterpret_cast<const float4*>(
          &obs[(size_t)(row0+m)*DIN + kt*16 + k4*4]);
    }
    int bk = tid >> 4;
    int bc = (tid & 15) * 4;
    float4 bv = *reinterpret_cast<const float4*>(
        &Wemb[(size_t)(kt*16+bk)*DK + col0 + bc]);
    __syncthreads();
#pragma unroll
    for (int r = 0; r < 2; ++r) {
      int idx = tid + 256*r;
      int m = idx >> 2, k4 = idx & 3;
      As[k4*4+0][m] = av[r].x;
      As[k4*4+1][m] = av[r].y;
      As[k4*4+2][m] = av[r].z;
      As[k4*4+3][m] = av[r].w;
    }
    *reinterpret_cast<float4*>(&Bs[bk][bc]) = bv;
    __syncthreads();
#pragma unroll
    for (int k = 0; k < 16; ++k) {
      float4 a0 = *reinterpret_cast<const float4*>(&As[k][tr*8]);
      float4 a1 = *reinterpret_cast<const float4*>(&As[k][tr*8+4]);
      float4 b0 = *reinterpret_cast<const float4*>(&Bs[k][tc*4]);
      float ar[8] = {a0.x,a0.y,a0.z,a0.w,a1.x,a1.y,a1.z,a1.w};
      float br[4] = {b0.x,b0.y,b0.z,b0.w};
#pragma unroll
      for (int i = 0; i < 8; ++i)
#pragma unroll
        for (int j = 0; j < 4; ++j)
          acc[i][j] = fmaf(ar[i], br[j], acc[i][j]);
    }
  }
  float4 bias = *reinterpret_cast<const float4*>(&bemb[col0 + tc*4]);
#pragma unroll
  for (int i = 0; i < 8; ++i) {
    float4 o;
    o.x = acc[i][0] + bias.x; o.y = acc[i][1] + bias.y;
    o.z = acc[i][2] + bias.z; o.w = acc[i][3] + bias.w;
    *reinterpret_cast<float4*>(
        &x[(size_t)(row0 + tr*8 + i)*DK + col0 + tc*4]) = o;
  }
}

// ---------------------------------------------------------------------------
// K2 (path A): hg = x @ W_hg with fused gate math + fused 128-step chunk scan.
// Block = 128 consecutive timesteps (one batch) x 64 DI channels.
// Emits per-chunk segment summaries (P = sum lc, V = scanned L) only.
// ---------------------------------------------------------------------------
__global__ __launch_bounds__(256) void hg_gemm_scan(
    const float* __restrict__ x, const float* __restrict__ Whg,
    float* __restrict__ chP, float* __restrict__ chL)
{
  __shared__ float As[16][132];
  __shared__ float Bs[16][128];   // [k][0..63]=hidden cols, [64..127]=gate cols
  const int tid = threadIdx.x;
  const int tr = tid >> 4, tc = tid & 15;
  const int row0 = blockIdx.x * 128;
  const int col0 = blockIdx.y * 64;
  float acch[8][4] = {};
  float accg[8][4] = {};

  for (int kt = 0; kt < DK/16; ++kt) {
    float4 av[2];
#pragma unroll
    for (int r = 0; r < 2; ++r) {
      int idx = tid + 256*r;
      int m = idx >> 2, k4 = idx & 3;
      av[r] = *reinterpret_cast<const float4*>(
          &x[(size_t)(row0+m)*DK + kt*16 + k4*4]);
    }
    float4 bv[2];
#pragma unroll
    for (int r = 0; r < 2; ++r) {
      int idx = tid + 256*r;
      int k = idx >> 5;
      int c4 = idx & 31;
      int col = (c4 < 16) ? (col0 + c4*4) : (DIEXP + col0 + (c4-16)*4);
      bv[r] = *reinterpret_cast<const float4*>(
          &Whg[(size_t)(kt*16+k)*NHG + col]);
    }
    __syncthreads();
#pragma unroll
    for (int r = 0; r < 2; ++r) {
      int idx = tid + 256*r;
      int m = idx >> 2, k4 = idx & 3;
      As[k4*4+0][m] = av[r].x;
      As[k4*4+1][m] = av[r].y;
      As[k4*4+2][m] = av[r].z;
      As[k4*4+3][m] = av[r].w;
    }
#pragma unroll
    for (int r = 0; r < 2; ++r) {
      int idx = tid + 256*r;
      int k = idx >> 5;
      int c4 = idx & 31;
      int scol = (c4 < 16) ? c4*4 : (64 + (c4-16)*4);
      *reinterpret_cast<float4*>(&Bs[k][scol]) = bv[r];
    }
    __syncthreads();
#pragma unroll
    for (int k = 0; k < 16; ++k) {
      float4 a0 = *reinterpret_cast<const float4*>(&As[k][tr*8]);
      float4 a1 = *reinterpret_cast<const float4*>(&As[k][tr*8+4]);
      float4 bh = *reinterpret_cast<const float4*>(&Bs[k][tc*4]);
      float4 bg = *reinterpret_cast<const float4*>(&Bs[k][64 + tc*4]);
      float ar[8] = {a0.x,a0.y,a0.z,a0.w,a1.x,a1.y,a1.z,a1.w};
      float bhr[4] = {bh.x,bh.y,bh.z,bh.w};
      float bgr[4] = {bg.x,bg.y,bg.z,bg.w};
#pragma unroll
      for (int i = 0; i < 8; ++i) {
#pragma unroll
        for (int j = 0; j < 4; ++j) {
          acch[i][j] = fmaf(ar[i], bhr[j], acch[i][j]);
          accg[i][j] = fmaf(ar[i], bgr[j], accg[i][j]);
        }
      }
    }
  }
  // ---- fused epilogue: per-thread scan over its 8 timesteps x 4 channels
  float P[4], V[4];
#pragma unroll
  for (int j = 0; j < 4; ++j) { P[j] = 0.f; V[j] = -INFINITY; }
#pragma unroll
  for (int i = 0; i < 8; ++i) {
#pragma unroll
    for (int j = 0; j < 4; ++j) {
      float lcv, lvv;
      gate_math(accg[i][j], acch[i][j], lcv, lvv);
      V[j] = lax(lcv, V[j], lvv);
      P[j] += lcv;
    }
  }
  __syncthreads();              // done reading As/Bs; reuse as scratch
#pragma unroll
  for (int j = 0; j < 4; ++j) {
    As[tr][tc*4+j] = P[j];
    Bs[tr][tc*4+j] = V[j];
  }
  __syncthreads();
  if (tid < 64) {               // combine 16 micro-segments in time order
    float Pa = 0.f, Va = -INFINITY;
#pragma unroll
    for (int t = 0; t < 16; ++t) {
      float Pc = As[t][tid], Vc = Bs[t][tid];
      Va = lax(Pc, Va, Vc);
      Pa += Pc;
    }
    int b = row0 / SS;
    int c = (row0 % SS) / TCH;
    size_t o = ((size_t)(b*CCH + c))*DIEXP + col0 + tid;
    chP[o] = Pa;
    chL[o] = Va;
  }
}

// ---------------------------------------------------------------------------
// K2' (path B, tiny-workspace): same as K2 but recomputes the needed x-chunk
// from obs @ W_emb on the fly (no x buffer).
// ---------------------------------------------------------------------------
__global__ __launch_bounds__(256) void hg_fused_scan(
    const float* __restrict__ obs, const float* __restrict__ Wemb,
    const float* __restrict__ bemb, const float* __restrict__ Whg,
    float* __restrict__ chP, float* __restrict__ chL)
{
  __shared__ float obsT[64][132];  // [k_in][m]
  __shared__ float xs[16][132];    // [kk][m] current x chunk
  __shared__ float Bs[16][128];
  __shared__ float WS[64][16];     // W_emb chunk [k_in][kk]
  const int tid = threadIdx.x;
  const int tr = tid >> 4, tc = tid & 15;
  const int row0 = blockIdx.x * 128;
  const int col0 = blockIdx.y * 64;
  float acch[8][4] = {};
  float accg[8][4] = {};

  // stage obs tile (transposed)
#pragma unroll
  for (int r = 0; r < 8; ++r) {
    int idx = tid + 256*r;         // 0..2047
    int m = idx >> 4, k4 = idx & 15;
    float4 o = *reinterpret_cast<const float4*>(
        &obs[(size_t)(row0+m)*DIN + k4*4]);
    obsT[k4*4+0][m] = o.x;
    obsT[k4*4+1][m] = o.y;
    obsT[k4*4+2][m] = o.z;
    obsT[k4*4+3][m] = o.w;
  }

  const int wk = tid >> 2, wc = (tid & 3) * 4;   // W_emb prefetch mapping
  float4 bv[2], wv;
  // prefetch kt = 0
  wv = *reinterpret_cast<const float4*>(&Wemb[(size_t)wk*DK + wc]);
#pragma unroll
  for (int r = 0; r < 2; ++r) {
    int idx = tid + 256*r;
    int k = idx >> 5;
    int c4 = idx & 31;
    int col = (c4 < 16) ? (col0 + c4*4) : (DIEXP + col0 + (c4-16)*4);
    bv[r] = *reinterpret_cast<const float4*>(&Whg[(size_t)k*NHG + col]);
  }

  const int mm = tid & 127;            // x-compute mapping
  const int kg = (tid >> 7) * 8;

  for (int kt = 0; kt < DK/16; ++kt) {
    if (kt > 0) __syncthreads();       // prev readers of xs/Bs/WS done
    *reinterpret_cast<float4*>(&WS[wk][wc]) = wv;
#pragma unroll
    for (int r = 0; r < 2; ++r) {
      int idx = tid + 256*r;
      int k = idx >> 5;
      int c4 = idx & 31;
      int scol = (c4 < 16) ? c4*4 : (64 + (c4-16)*4);
      *reinterpret_cast<float4*>(&Bs[k][scol]) = bv[r];
    }
    if (kt < DK/16 - 1) {              // prefetch next
      int ktn = kt + 1;
      wv = *reinterpret_cast<const float4*>(
          &Wemb[(size_t)wk*DK + ktn*16 + wc]);
#pragma unroll
      for (int r = 0; r < 2; ++r) {
        int idx = tid + 256*r;
        int k = idx >> 5;
        int c4 = idx & 31;
        int col = (c4 < 16) ? (col0 + c4*4) : (DIEXP + col0 + (c4-16)*4);
        bv[r] = *reinterpret_cast<const float4*>(
            &Whg[(size_t)(ktn*16+k)*NHG + col]);
      }
    }
    __syncthreads();                   // WS (and obsT first iter) visible
    // compute x chunk: xs[kg..kg+7][mm]
    float xa[8];
#pragma unroll
    for (int j = 0; j < 8; ++j) xa[j] = bemb[kt*16 + kg + j];
#pragma unroll 8
    for (int k64 = 0; k64 < 64; ++k64) {
      float a = obsT[k64][mm];
#pragma unroll
      for (int j = 0; j < 8; ++j) xa[j] = fmaf(a, WS[k64][kg+j], xa[j]);
    }
#pragma unroll
    for (int j = 0; j < 8; ++j) xs[kg+j][mm] = xa[j];
    __syncthreads();                   // xs, Bs visible
#pragma unroll
    for (int k = 0; k < 16; ++k) {
      float4 a0 = *reinterpret_cast<const float4*>(&xs[k][tr*8]);
      float4 a1 = *reinterpret_cast<const float4*>(&xs[k][tr*8+4]);
      float4 bh = *reinterpret_cast<const float4*>(&Bs[k][tc*4]);
      float4 bg = *reinterpret_cast<const float4*>(&Bs[k][64 + tc*4]);
      float ar[8] = {a0.x,a0.y,a0.z,a0.w,a1.x,a1.y,a1.z,a1.w};
      float bhr[4] = {bh.x,bh.y,bh.z,bh.w};
      float bgr[4] = {bg.x,bg.y,bg.z,bg.w};
#pragma unroll
      for (int i = 0; i < 8; ++i) {
#pragma unroll
        for (int j = 0; j < 4; ++j) {
          acch[i][j] = fmaf(ar[i], bhr[j], acch[i][j]);
          accg[i][j] = fmaf(ar[i], bgr[j], accg[i][j]);
        }
      }
    }
  }
  // ---- fused epilogue (identical to path A)
  float P[4], V[4];
#pragma unroll
  for (int j = 0; j < 4; ++j) { P[j] = 0.f; V[j] = -INFINITY; }
#pragma unroll
  for (int i = 0; i < 8; ++i) {
#pragma unroll
    for (int j = 0; j < 4; ++j) {
      float lcv, lvv;
      gate_math(accg[i][j], acch[i][j], lcv, lvv);
      V[j] = lax(lcv, V[j], lvv);
      P[j] += lcv;
    }
  }
  __syncthreads();
#pragma unroll
  for (int j = 0; j < 4; ++j) {
    xs[tr][tc*4+j] = P[j];
    Bs[tr][tc*4+j] = V[j];
  }
  __syncthreads();
  if (tid < 64) {
    float Pa = 0.f, Va = -INFINITY;
#pragma unroll
    for (int t = 0; t < 16; ++t) {
      float Pc = xs[t][tid], Vc = Bs[t][tid];
      Va = lax(Pc, Va, Vc);
      Pa += Pc;
    }
    int b = row0 / SS;
    int c = (row0 % SS) / TCH;
    size_t o = ((size_t)(b*CCH + c))*DIEXP + col0 + tid;
    chP[o] = Pa;
    chL[o] = Va;
  }
}

// ---------------------------------------------------------------------------
// K3: combine the 32 chunk summaries per channel, h_last = exp(L)
// ---------------------------------------------------------------------------
__global__ __launch_bounds__(256) void combine_chunks(
    const float* __restrict__ chP, const float* __restrict__ chL,
    float* __restrict__ hl)
{
  int ch = blockIdx.x*256 + threadIdx.x;   // < NCHAN
  int b = ch / DIEXP, i = ch % DIEXP;
  float L = -INFINITY;
#pragma unroll
  for (int c = 0; c < CCH; ++c) {
    size_t o = ((size_t)(b*CCH + c))*DIEXP + i;
    L = lax(chP[o], L, chL[o]);
  }
  hl[ch] = __expf(L);
}

// ---------------------------------------------------------------------------
// K4: out = h_last @ W_out
// ---------------------------------------------------------------------------
__global__ __launch_bounds__(512) void out_gemm(
    const float* __restrict__ hl, const float* __restrict__ Wout,
    float* __restrict__ out)
{
  __shared__ float hs[DIEXP];
  int b = blockIdx.x;
  for (int i = threadIdx.x; i < DIEXP; i += 512) hs[i] = hl[b*DIEXP + i];
  __syncthreads();
  int d = threadIdx.x;
  float s = 0.f;
#pragma unroll 8
  for (int i = 0; i < DIEXP; ++i)
    s = fmaf(hs[i], Wout[(size_t)i*DK + d], s);
  out[(size_t)b*DK + d] = s;
}

// ---------------------------------------------------------------------------
extern "C" void kernel_launch(void* const* d_in, const int* in_sizes, int n_in,
                              void* d_out, int out_size, void* d_ws, size_t ws_size,
                              hipStream_t stream) {
  const float* obs  = (const float*)d_in[0];
  const float* Wemb = (const float*)d_in[1];
  const float* bemb = (const float*)d_in[2];
  const float* Whg  = (const float*)d_in[3];
  const float* Wout = (const float*)d_in[4];
  float* out = (float*)d_out;

  float* ws  = (float*)d_ws;
  float* chP = ws;                                  // NB*CCH*DIEXP
  float* chL = chP + (size_t)NB*CCH*DIEXP;          // NB*CCH*DIEXP
  float* hl  = chL + (size_t)NB*CCH*DIEXP;          // NCHAN
  float* x   = hl + NCHAN;                          // MROWS*DK (path A only)

  const size_t needA = ((size_t)NB*CCH*DIEXP*2 + NCHAN + (size_t)MROWS*DK)
                       * sizeof(float);

  if (ws_size >= needA) {
    emb_gemm<<<dim3(MROWS/128, DK/64), 256, 0, stream>>>(obs, Wemb, bemb, x);
    hg_gemm_scan<<<dim3(MROWS/128, DIEXP/64), 256, 0, stream>>>(x, Whg, chP, chL);
  } else {
    hg_fused_scan<<<dim3(MROWS/128, DIEXP/64), 256, 0, stream>>>(
        obs, Wemb, bemb, Whg, chP, chL);
  }
  combine_chunks<<<dim3(NCHAN/256), 256, 0, stream>>>(chP, chL, hl);
  out_gemm<<<dim3(NB), 512, 0, stream>>>(hl, Wout, out);
}

// Round 3
// 916.847 us; speedup vs baseline: 1.5374x; 1.5374x over previous
//
#include <hip/hip_runtime.h>
#include <cstdint>
#include <cstddef>
#include <math.h>

// Problem dims
#define NB    16
#define SS    4096
#define DIN   64
#define DK    512
#define DIEXP 768
#define MROWS (NB*SS)      // 65536
#define NHG   (2*DIEXP)    // 1536
#define CCH   32           // chunks per sequence (chunk len 128)
#define TCH   128
#define NCHAN (NB*DIEXP)   // 12288

typedef __attribute__((ext_vector_type(8))) short short8;   // 8 bf16
typedef __attribute__((ext_vector_type(4))) float f32x4;

__device__ __forceinline__ unsigned short f2bf(float f) {
  unsigned u = __builtin_bit_cast(unsigned, f);
  u += 0x7FFFu + ((u >> 16) & 1u);          // RNE
  return (unsigned short)(u >> 16);
}
__device__ __forceinline__ float bf2f(unsigned short h) {
  unsigned u = ((unsigned)h) << 16;
  return __builtin_bit_cast(float, u);
}

__device__ __forceinline__ float lax(float P, float L, float V) {
  // logaddexp(P + L, V); L may be -inf
  float xx = P + L;
  float m  = fmaxf(xx, V);
  float d  = fminf(xx, V) - m;
  return m + __logf(1.f + __expf(d));
}

__device__ __forceinline__ void gate_math(float g, float h, float& lcv, float& lvv) {
  float spg  = fmaxf(g, 0.f) + __logf(1.f + __expf(-fabsf(g)));   // softplus(g)
  float logg = (h >= 0.f) ? __logf(h + 0.5f)
                          : (h - __logf(1.f + __expf(h)));        // log g(h)
  lcv = -spg;
  lvv = g - spg + logg;
}

// ---------------------------------------------------------------------------
// W pre-transpose + bf16 hi/lo split: WT[j][k] = W_hg[k][j]
// ---------------------------------------------------------------------------
__global__ __launch_bounds__(256) void wsplit(
    const float* __restrict__ W, unsigned short* __restrict__ WT_hi,
    unsigned short* __restrict__ WT_lo)
{
  int j = blockIdx.x;                 // 0..1535
  for (int k = threadIdx.x; k < DK; k += 256) {
    float w = W[(size_t)k*NHG + j];
    unsigned short h = f2bf(w);
    unsigned short l = f2bf(w - bf2f(h));
    WT_hi[(size_t)j*DK + k] = h;
    WT_lo[(size_t)j*DK + k] = l;
  }
}

// ---------------------------------------------------------------------------
// K1: x = obs @ W_emb + b_emb  -> bf16 hi/lo pair
// ---------------------------------------------------------------------------
__global__ __launch_bounds__(256) void emb_gemm_bf(
    const float* __restrict__ obs, const float* __restrict__ Wemb,
    const float* __restrict__ bemb, unsigned short* __restrict__ xhi,
    unsigned short* __restrict__ xlo)
{
  __shared__ float As[16][132];
  __shared__ float Bs[16][64];
  const int tid = threadIdx.x;
  const int tr = tid >> 4, tc = tid & 15;
  const int row0 = blockIdx.x * 128;
  const int col0 = blockIdx.y * 64;
  float acc[8][4] = {};

  for (int kt = 0; kt < DIN/16; ++kt) {
    float4 av[2];
#pragma unroll
    for (int r = 0; r < 2; ++r) {
      int idx = tid + 256*r;
      int m = idx >> 2, k4 = idx & 3;
      av[r] = *reinterpret_cast<const float4*>(
          &obs[(size_t)(row0+m)*DIN + kt*16 + k4*4]);
    }
    int bk = tid >> 4;
    int bc = (tid & 15) * 4;
    float4 bv = *reinterpret_cast<const float4*>(
        &Wemb[(size_t)(kt*16+bk)*DK + col0 + bc]);
    __syncthreads();
#pragma unroll
    for (int r = 0; r < 2; ++r) {
      int idx = tid + 256*r;
      int m = idx >> 2, k4 = idx & 3;
      As[k4*4+0][m] = av[r].x;
      As[k4*4+1][m] = av[r].y;
      As[k4*4+2][m] = av[r].z;
      As[k4*4+3][m] = av[r].w;
    }
    *reinterpret_cast<float4*>(&Bs[bk][bc]) = bv;
    __syncthreads();
#pragma unroll
    for (int k = 0; k < 16; ++k) {
      float4 a0 = *reinterpret_cast<const float4*>(&As[k][tr*8]);
      float4 a1 = *reinterpret_cast<const float4*>(&As[k][tr*8+4]);
      float4 b0 = *reinterpret_cast<const float4*>(&Bs[k][tc*4]);
      float ar[8] = {a0.x,a0.y,a0.z,a0.w,a1.x,a1.y,a1.z,a1.w};
      float br[4] = {b0.x,b0.y,b0.z,b0.w};
#pragma unroll
      for (int i = 0; i < 8; ++i)
#pragma unroll
        for (int j = 0; j < 4; ++j)
          acc[i][j] = fmaf(ar[i], br[j], acc[i][j]);
    }
  }
  float4 bias = *reinterpret_cast<const float4*>(&bemb[col0 + tc*4]);
  float bb[4] = {bias.x, bias.y, bias.z, bias.w};
#pragma unroll
  for (int i = 0; i < 8; ++i) {
    size_t rowi = (size_t)(row0 + tr*8 + i);
    ushort4 oh, ol;
    unsigned short* ph = reinterpret_cast<unsigned short*>(&oh);
    unsigned short* pl = reinterpret_cast<unsigned short*>(&ol);
#pragma unroll
    for (int j = 0; j < 4; ++j) {
      float f = acc[i][j] + bb[j];
      unsigned short h = f2bf(f);
      ph[j] = h;
      pl[j] = f2bf(f - bf2f(h));
    }
    *reinterpret_cast<ushort4*>(&xhi[rowi*DK + col0 + tc*4]) = oh;
    *reinterpret_cast<ushort4*>(&xlo[rowi*DK + col0 + tc*4]) = ol;
  }
}

// ---------------------------------------------------------------------------
// K2: split-bf16 MFMA GEMM (3-pass: xh*Wh + xh*Wl + xl*Wh) + fused gate math
// + fused 128-step chunk scan. BM=128 rows (one chunk), 256 tile cols =
// 128 h/g channel pairs. 4 waves, each 128 rows x 64 cols (8m x 4n frags).
// B cols interleaved in 16-col groups: h,g,h,g -> gate pairing lane-local.
// LDS swizzle: phys_slot = log_slot ^ ((row>>1)&3)  (2-way free on r/w).
// ---------------------------------------------------------------------------
__global__ __launch_bounds__(256, 2) void hg_mfma_scan(
    const unsigned short* __restrict__ xhi, const unsigned short* __restrict__ xlo,
    const unsigned short* __restrict__ wthi, const unsigned short* __restrict__ wtlo,
    float* __restrict__ chP, float* __restrict__ chL)
{
  __shared__ char smem[49152];   // Ah 8K | Al 8K | Bh 16K | Bl 16K
  const int t = threadIdx.x;
  const int row0 = blockIdx.x * 128;
  const int colbase = blockIdx.y * 128;   // channel base (128 channels/block)

  // --- staging maps (constant across kt) ---
  size_t asrc[2]; int alds[2];
#pragma unroll
  for (int q = 0; q < 2; ++q) {
    int i = t + 256*q;
    int r = i >> 2, s = i & 3;
    int slog = s ^ ((r >> 1) & 3);
    asrc[q] = (size_t)(row0 + r)*DK + slog*8;
    alds[q] = r*64 + s*16;
  }
  size_t bsrc[4]; int blds[4];
#pragma unroll
  for (int q = 0; q < 4; ++q) {
    int i = t + 256*q;
    int c = i >> 2, s = i & 3;
    int slog = s ^ ((c >> 1) & 3);
    int grp = c >> 4, u = c & 15;
    int wr = ((grp & 1) ? DIEXP : 0) + colbase + (grp >> 1)*16 + u;
    bsrc[q] = (size_t)wr*DK + slog*8;
    blds[q] = c*64 + s*16;
  }

  // --- fragment read maps ---
  const int w  = t >> 6;        // wave 0..3 -> cols 64w..64w+63
  const int l  = t & 63;
  const int u  = l & 15;
  const int qh = l >> 4;
  const int phys = qh ^ ((u >> 1) & 3);
  const int aoff_h = u*64 + phys*16;                      // + m*1024
  const int aoff_l = 8192 + aoff_h;
  const int boff_h = 16384 + (w*64 + u)*64 + phys*16;     // + n*1024
  const int boff_l = 16384 + boff_h;

  f32x4 acc[8][4];
#pragma unroll
  for (int m = 0; m < 8; ++m)
#pragma unroll
    for (int n = 0; n < 4; ++n)
      acc[m][n] = (f32x4){0.f, 0.f, 0.f, 0.f};

  uint4 ra[2], rl[2], rb[4], rc[4];
  // prologue loads (kt = 0)
#pragma unroll
  for (int q = 0; q < 2; ++q) {
    ra[q] = *reinterpret_cast<const uint4*>(xhi + asrc[q]);
    rl[q] = *reinterpret_cast<const uint4*>(xlo + asrc[q]);
  }
#pragma unroll
  for (int q = 0; q < 4; ++q) {
    rb[q] = *reinterpret_cast<const uint4*>(wthi + bsrc[q]);
    rc[q] = *reinterpret_cast<const uint4*>(wtlo + bsrc[q]);
  }

#pragma unroll 1
  for (int kt = 0; kt < DK/32; ++kt) {
    __syncthreads();            // prev tile consumers done
#pragma unroll
    for (int q = 0; q < 2; ++q) {
      *reinterpret_cast<uint4*>(smem + alds[q])         = ra[q];
      *reinterpret_cast<uint4*>(smem + 8192 + alds[q])  = rl[q];
    }
#pragma unroll
    for (int q = 0; q < 4; ++q) {
      *reinterpret_cast<uint4*>(smem + 16384 + blds[q]) = rb[q];
      *reinterpret_cast<uint4*>(smem + 32768 + blds[q]) = rc[q];
    }
    __syncthreads();            // tile visible
    if (kt < DK/32 - 1) {       // prefetch next (hides under MFMA cluster)
      int ko = (kt + 1) * 32;
#pragma unroll
      for (int q = 0; q < 2; ++q) {
        ra[q] = *reinterpret_cast<const uint4*>(xhi + asrc[q] + ko);
        rl[q] = *reinterpret_cast<const uint4*>(xlo + asrc[q] + ko);
      }
#pragma unroll
      for (int q = 0; q < 4; ++q) {
        rb[q] = *reinterpret_cast<const uint4*>(wthi + bsrc[q] + ko);
        rc[q] = *reinterpret_cast<const uint4*>(wtlo + bsrc[q] + ko);
      }
    }
    short8 bh[4], bl[4];
#pragma unroll
    for (int n = 0; n < 4; ++n) {
      bh[n] = *reinterpret_cast<const short8*>(smem + boff_h + n*1024);
      bl[n] = *reinterpret_cast<const short8*>(smem + boff_l + n*1024);
    }
#pragma unroll
    for (int m = 0; m < 8; ++m) {
      short8 ah = *reinterpret_cast<const short8*>(smem + aoff_h + m*1024);
      short8 al = *reinterpret_cast<const short8*>(smem + aoff_l + m*1024);
#pragma unroll
      for (int n = 0; n < 4; ++n) {
        acc[m][n] = __builtin_amdgcn_mfma_f32_16x16x32_bf16(ah, bh[n], acc[m][n], 0, 0, 0);
        acc[m][n] = __builtin_amdgcn_mfma_f32_16x16x32_bf16(ah, bl[n], acc[m][n], 0, 0, 0);
        acc[m][n] = __builtin_amdgcn_mfma_f32_16x16x32_bf16(al, bh[n], acc[m][n], 0, 0, 0);
      }
    }
  }

  // ---- fused gate math + chunk scan (wave-local: 128 rows x 32 channels) ----
  __syncthreads();              // all tile reads done; overlay segment scratch
  float* segP = reinterpret_cast<float*>(smem);            // 16 KB
  float* segV = reinterpret_cast<float*>(smem + 16384);    // 16 KB
  // C/D layout: col = lane&15, row = (lane>>4)*4 + reg. Lane's 4 regs are
  // 4 consecutive timesteps -> per-lane 4-step segment summary.
#pragma unroll
  for (int p = 0; p < 2; ++p) {        // channel pair group (n=2p:h, 2p+1:g)
#pragma unroll
    for (int m = 0; m < 8; ++m) {
      float P = 0.f, V = -INFINITY;
#pragma unroll
      for (int r = 0; r < 4; ++r) {
        float lcv, lvv;
        gate_math(acc[m][2*p+1][r], acc[m][2*p][r], lcv, lvv);  // (g, h)
        V = lax(lcv, V, lvv);
        P += lcv;
      }
      int sidx = w*1024 + ((m*4 + qh)*2 + p)*16 + u;
      segP[sidx] = P;
      segV[sidx] = V;
    }
  }
  __syncthreads();
  if (l < 32) {                        // 32 channels per wave
    int p = l >> 4, uu = l & 15;
    float Pa = 0.f, Va = -INFINITY;
#pragma unroll
    for (int mm = 0; mm < 8; ++mm)     // time order: m major, hi minor
#pragma unroll
      for (int hh = 0; hh < 4; ++hh) {
        int sidx = w*1024 + ((mm*4 + hh)*2 + p)*16 + uu;
        float Ps = segP[sidx], Vs = segV[sidx];
        Va = lax(Ps, Va, Vs);
        Pa += Ps;
      }
    int b = row0 >> 12;                // row0 / 4096
    int c = (row0 & 4095) >> 7;        // chunk within sequence
    int j = colbase + 32*w + p*16 + uu;
    size_t o = ((size_t)(b*CCH + c))*DIEXP + j;
    chP[o] = Pa;
    chL[o] = Va;
  }
}

// ---------------------------------------------------------------------------
// Fallback path (round-2, proven): fp32 x + VALU GEMM + fused scan
// ---------------------------------------------------------------------------
__global__ __launch_bounds__(256) void emb_gemm(
    const float* __restrict__ obs, const float* __restrict__ Wemb,
    const float* __restrict__ bemb, float* __restrict__ x)
{
  __shared__ float As[16][132];
  __shared__ float Bs[16][64];
  const int tid = threadIdx.x;
  const int tr = tid >> 4, tc = tid & 15;
  const int row0 = blockIdx.x * 128;
  const int col0 = blockIdx.y * 64;
  float acc[8][4] = {};
  for (int kt = 0; kt < DIN/16; ++kt) {
    float4 av[2];
#pragma unroll
    for (int r = 0; r < 2; ++r) {
      int idx = tid + 256*r;
      int m = idx >> 2, k4 = idx & 3;
      av[r] = *reinterpret_cast<const float4*>(
          &obs[(size_t)(row0+m)*DIN + kt*16 + k4*4]);
    }
    int bk = tid >> 4;
    int bc = (tid & 15) * 4;
    float4 bv = *reinterpret_cast<const float4*>(
        &Wemb[(size_t)(kt*16+bk)*DK + col0 + bc]);
    __syncthreads();
#pragma unroll
    for (int r = 0; r < 2; ++r) {
      int idx = tid + 256*r;
      int m = idx >> 2, k4 = idx & 3;
      As[k4*4+0][m] = av[r].x;
      As[k4*4+1][m] = av[r].y;
      As[k4*4+2][m] = av[r].z;
      As[k4*4+3][m] = av[r].w;
    }
    *reinterpret_cast<float4*>(&Bs[bk][bc]) = bv;
    __syncthreads();
#pragma unroll
    for (int k = 0; k < 16; ++k) {
      float4 a0 = *reinterpret_cast<const float4*>(&As[k][tr*8]);
      float4 a1 = *reinterpret_cast<const float4*>(&As[k][tr*8+4]);
      float4 b0 = *reinterpret_cast<const float4*>(&Bs[k][tc*4]);
      float ar[8] = {a0.x,a0.y,a0.z,a0.w,a1.x,a1.y,a1.z,a1.w};
      float br[4] = {b0.x,b0.y,b0.z,b0.w};
#pragma unroll
      for (int i = 0; i < 8; ++i)
#pragma unroll
        for (int j = 0; j < 4; ++j)
          acc[i][j] = fmaf(ar[i], br[j], acc[i][j]);
    }
  }
  float4 bias = *reinterpret_cast<const float4*>(&bemb[col0 + tc*4]);
#pragma unroll
  for (int i = 0; i < 8; ++i) {
    float4 o;
    o.x = acc[i][0] + bias.x; o.y = acc[i][1] + bias.y;
    o.z = acc[i][2] + bias.z; o.w = acc[i][3] + bias.w;
    *reinterpret_cast<float4*>(
        &x[(size_t)(row0 + tr*8 + i)*DK + col0 + tc*4]) = o;
  }
}

__global__ __launch_bounds__(256) void hg_gemm_scan(
    const float* __restrict__ x, const float* __restrict__ Whg,
    float* __restrict__ chP, float* __restrict__ chL)
{
  __shared__ float As[16][132];
  __shared__ float Bs[16][128];
  const int tid = threadIdx.x;
  const int tr = tid >> 4, tc = tid & 15;
  const int row0 = blockIdx.x * 128;
  const int col0 = blockIdx.y * 64;
  float acch[8][4] = {};
  float accg[8][4] = {};
  for (int kt = 0; kt < DK/16; ++kt) {
    float4 av[2];
#pragma unroll
    for (int r = 0; r < 2; ++r) {
      int idx = tid + 256*r;
      int m = idx >> 2, k4 = idx & 3;
      av[r] = *reinterpret_cast<const float4*>(
          &x[(size_t)(row0+m)*DK + kt*16 + k4*4]);
    }
    float4 bv[2];
#pragma unroll
    for (int r = 0; r < 2; ++r) {
      int idx = tid + 256*r;
      int k = idx >> 5;
      int c4 = idx & 31;
      int col = (c4 < 16) ? (col0 + c4*4) : (DIEXP + col0 + (c4-16)*4);
      bv[r] = *reinterpret_cast<const float4*>(
          &Whg[(size_t)(kt*16+k)*NHG + col]);
    }
    __syncthreads();
#pragma unroll
    for (int r = 0; r < 2; ++r) {
      int idx = tid + 256*r;
      int m = idx >> 2, k4 = idx & 3;
      As[k4*4+0][m] = av[r].x;
      As[k4*4+1][m] = av[r].y;
      As[k4*4+2][m] = av[r].z;
      As[k4*4+3][m] = av[r].w;
    }
#pragma unroll
    for (int r = 0; r < 2; ++r) {
      int idx = tid + 256*r;
      int k = idx >> 5;
      int c4 = idx & 31;
      int scol = (c4 < 16) ? c4*4 : (64 + (c4-16)*4);
      *reinterpret_cast<float4*>(&Bs[k][scol]) = bv[r];
    }
    __syncthreads();
#pragma unroll
    for (int k = 0; k < 16; ++k) {
      float4 a0 = *reinterpret_cast<const float4*>(&As[k][tr*8]);
      float4 a1 = *reinterpret_cast<const float4*>(&As[k][tr*8+4]);
      float4 bh = *reinterpret_cast<const float4*>(&Bs[k][tc*4]);
      float4 bg = *reinterpret_cast<const float4*>(&Bs[k][64 + tc*4]);
      float ar[8] = {a0.x,a0.y,a0.z,a0.w,a1.x,a1.y,a1.z,a1.w};
      float bhr[4] = {bh.x,bh.y,bh.z,bh.w};
      float bgr[4] = {bg.x,bg.y,bg.z,bg.w};
#pragma unroll
      for (int i = 0; i < 8; ++i) {
#pragma unroll
        for (int j = 0; j < 4; ++j) {
          acch[i][j] = fmaf(ar[i], bhr[j], acch[i][j]);
          accg[i][j] = fmaf(ar[i], bgr[j], accg[i][j]);
        }
      }
    }
  }
  float P[4], V[4];
#pragma unroll
  for (int j = 0; j < 4; ++j) { P[j] = 0.f; V[j] = -INFINITY; }
#pragma unroll
  for (int i = 0; i < 8; ++i) {
#pragma unroll
    for (int j = 0; j < 4; ++j) {
      float lcv, lvv;
      gate_math(accg[i][j], acch[i][j], lcv, lvv);
      V[j] = lax(lcv, V[j], lvv);
      P[j] += lcv;
    }
  }
  __syncthreads();
#pragma unroll
  for (int j = 0; j < 4; ++j) {
    As[tr][tc*4+j] = P[j];
    Bs[tr][tc*4+j] = V[j];
  }
  __syncthreads();
  if (tid < 64) {
    float Pa = 0.f, Va = -INFINITY;
#pragma unroll
    for (int t2 = 0; t2 < 16; ++t2) {
      float Pc = As[t2][tid], Vc = Bs[t2][tid];
      Va = lax(Pc, Va, Vc);
      Pa += Pc;
    }
    int b = row0 / SS;
    int c = (row0 % SS) / TCH;
    size_t o = ((size_t)(b*CCH + c))*DIEXP + col0 + tid;
    chP[o] = Pa;
    chL[o] = Va;
  }
}

// ---------------------------------------------------------------------------
// K3: combine chunk summaries; K4: out = h_last @ W_out
// ---------------------------------------------------------------------------
__global__ __launch_bounds__(256) void combine_chunks(
    const float* __restrict__ chP, const float* __restrict__ chL,
    float* __restrict__ hl)
{
  int ch = blockIdx.x*256 + threadIdx.x;
  int b = ch / DIEXP, i = ch % DIEXP;
  float L = -INFINITY;
#pragma unroll
  for (int c = 0; c < CCH; ++c) {
    size_t o = ((size_t)(b*CCH + c))*DIEXP + i;
    L = lax(chP[o], L, chL[o]);
  }
  hl[ch] = __expf(L);
}

__global__ __launch_bounds__(512) void out_gemm(
    const float* __restrict__ hl, const float* __restrict__ Wout,
    float* __restrict__ out)
{
  __shared__ float hs[DIEXP];
  int b = blockIdx.x;
  for (int i = threadIdx.x; i < DIEXP; i += 512) hs[i] = hl[b*DIEXP + i];
  __syncthreads();
  int d = threadIdx.x;
  float s = 0.f;
#pragma unroll 8
  for (int i = 0; i < DIEXP; ++i)
    s = fmaf(hs[i], Wout[(size_t)i*DK + d], s);
  out[(size_t)b*DK + d] = s;
}

// ---------------------------------------------------------------------------
extern "C" void kernel_launch(void* const* d_in, const int* in_sizes, int n_in,
                              void* d_out, int out_size, void* d_ws, size_t ws_size,
                              hipStream_t stream) {
  const float* obs  = (const float*)d_in[0];
  const float* Wemb = (const float*)d_in[1];
  const float* bemb = (const float*)d_in[2];
  const float* Whg  = (const float*)d_in[3];
  const float* Wout = (const float*)d_in[4];
  float* out = (float*)d_out;

  char* ws = (char*)d_ws;
  float* chP = (float*)ws;                                  // 1,572,864 B
  float* chL = (float*)(ws + 1572864);                      // 1,572,864 B
  float* hl  = (float*)(ws + 3145728);                      //    49,152 B
  // new path:
  unsigned short* wthi = (unsigned short*)(ws + 3194880);   // 1,572,864 B
  unsigned short* wtlo = (unsigned short*)(ws + 4767744);   // 1,572,864 B
  unsigned short* xhi  = (unsigned short*)(ws + 6340608);   // 67,108,864 B
  unsigned short* xlo  = (unsigned short*)(ws + 73449472);  // 67,108,864 B
  const size_t needNew = 140558336;
  // fallback:
  float* xf = (float*)(ws + 3194880);                       // 134,217,728 B
  const size_t needOld = 137412608;

  if (ws_size >= needNew) {
    wsplit<<<dim3(NHG), 256, 0, stream>>>(Whg, wthi, wtlo);
    emb_gemm_bf<<<dim3(MROWS/128, DK/64), 256, 0, stream>>>(obs, Wemb, bemb, xhi, xlo);
    hg_mfma_scan<<<dim3(MROWS/128, DIEXP/128), 256, 0, stream>>>(
        xhi, xlo, wthi, wtlo, chP, chL);
  } else if (ws_size >= needOld) {
    emb_gemm<<<dim3(MROWS/128, DK/64), 256, 0, stream>>>(obs, Wemb, bemb, xf);
    hg_gemm_scan<<<dim3(MROWS/128, DIEXP/64), 256, 0, stream>>>(xf, Whg, chP, chL);
  }
  combine_chunks<<<dim3(NCHAN/256), 256, 0, stream>>>(chP, chL, hl);
  out_gemm<<<dim3(NB), 512, 0, stream>>>(hl, Wout, out);
}

// Round 4
// 483.847 us; speedup vs baseline: 2.9133x; 1.8949x over previous
//
#include <hip/hip_runtime.h>
#include <cstdint>
#include <cstddef>
#include <math.h>

// Problem dims
#define NB    16
#define SS    4096
#define DIN   64
#define DK    512
#define DIEXP 768
#define MROWS (NB*SS)      // 65536
#define NHG   (2*DIEXP)    // 1536
#define CCH   32           // chunks per sequence (chunk len 128)
#define TCH   128
#define NCHAN (NB*DIEXP)   // 12288

typedef __attribute__((ext_vector_type(8))) short short8;   // 8 bf16
typedef __attribute__((ext_vector_type(4))) float f32x4;

#define GL2LDS16(g, lp) \
  __builtin_amdgcn_global_load_lds( \
      (const __attribute__((address_space(1))) void*)(g), \
      (__attribute__((address_space(3))) void*)(lp), 16, 0, 0)

__device__ __forceinline__ unsigned short f2bf(float f) {
  unsigned u = __builtin_bit_cast(unsigned, f);
  u += 0x7FFFu + ((u >> 16) & 1u);          // RNE
  return (unsigned short)(u >> 16);
}
__device__ __forceinline__ float bf2f(unsigned short h) {
  unsigned u = ((unsigned)h) << 16;
  return __builtin_bit_cast(float, u);
}

__device__ __forceinline__ float lax(float P, float L, float V) {
  // logaddexp(P + L, V); L may be -inf
  float xx = P + L;
  float m  = fmaxf(xx, V);
  float d  = fminf(xx, V) - m;
  return m + __logf(1.f + __expf(d));
}

__device__ __forceinline__ void gate_math(float g, float h, float& lcv, float& lvv) {
  float spg  = fmaxf(g, 0.f) + __logf(1.f + __expf(-fabsf(g)));   // softplus(g)
  float logg = (h >= 0.f) ? __logf(h + 0.5f)
                          : (h - __logf(1.f + __expf(h)));        // log g(h)
  lcv = -spg;
  lvv = g - spg + logg;
}

// ---------------------------------------------------------------------------
// W pre-transpose + bf16 hi/lo split: WT[j][k] = W_hg[k][j]
// ---------------------------------------------------------------------------
__global__ __launch_bounds__(256) void wsplit(
    const float* __restrict__ W, unsigned short* __restrict__ WT_hi,
    unsigned short* __restrict__ WT_lo)
{
  int j = blockIdx.x;                 // 0..1535
  for (int k = threadIdx.x; k < DK; k += 256) {
    float w = W[(size_t)k*NHG + j];
    unsigned short h = f2bf(w);
    unsigned short l = f2bf(w - bf2f(h));
    WT_hi[(size_t)j*DK + k] = h;
    WT_lo[(size_t)j*DK + k] = l;
  }
}

// ---------------------------------------------------------------------------
// K1: x = obs @ W_emb + b_emb  -> bf16 hi/lo pair
// ---------------------------------------------------------------------------
__global__ __launch_bounds__(256) void emb_gemm_bf(
    const float* __restrict__ obs, const float* __restrict__ Wemb,
    const float* __restrict__ bemb, unsigned short* __restrict__ xhi,
    unsigned short* __restrict__ xlo)
{
  __shared__ float As[16][132];
  __shared__ float Bs[16][64];
  const int tid = threadIdx.x;
  const int tr = tid >> 4, tc = tid & 15;
  const int row0 = blockIdx.x * 128;
  const int col0 = blockIdx.y * 64;
  float acc[8][4] = {};

  for (int kt = 0; kt < DIN/16; ++kt) {
    float4 av[2];
#pragma unroll
    for (int r = 0; r < 2; ++r) {
      int idx = tid + 256*r;
      int m = idx >> 2, k4 = idx & 3;
      av[r] = *reinterpret_cast<const float4*>(
          &obs[(size_t)(row0+m)*DIN + kt*16 + k4*4]);
    }
    int bk = tid >> 4;
    int bc = (tid & 15) * 4;
    float4 bv = *reinterpret_cast<const float4*>(
        &Wemb[(size_t)(kt*16+bk)*DK + col0 + bc]);
    __syncthreads();
#pragma unroll
    for (int r = 0; r < 2; ++r) {
      int idx = tid + 256*r;
      int m = idx >> 2, k4 = idx & 3;
      As[k4*4+0][m] = av[r].x;
      As[k4*4+1][m] = av[r].y;
      As[k4*4+2][m] = av[r].z;
      As[k4*4+3][m] = av[r].w;
    }
    *reinterpret_cast<float4*>(&Bs[bk][bc]) = bv;
    __syncthreads();
#pragma unroll
    for (int k = 0; k < 16; ++k) {
      float4 a0 = *reinterpret_cast<const float4*>(&As[k][tr*8]);
      float4 a1 = *reinterpret_cast<const float4*>(&As[k][tr*8+4]);
      float4 b0 = *reinterpret_cast<const float4*>(&Bs[k][tc*4]);
      float ar[8] = {a0.x,a0.y,a0.z,a0.w,a1.x,a1.y,a1.z,a1.w};
      float br[4] = {b0.x,b0.y,b0.z,b0.w};
#pragma unroll
      for (int i = 0; i < 8; ++i)
#pragma unroll
        for (int j = 0; j < 4; ++j)
          acc[i][j] = fmaf(ar[i], br[j], acc[i][j]);
    }
  }
  float4 bias = *reinterpret_cast<const float4*>(&bemb[col0 + tc*4]);
  float bb[4] = {bias.x, bias.y, bias.z, bias.w};
#pragma unroll
  for (int i = 0; i < 8; ++i) {
    size_t rowi = (size_t)(row0 + tr*8 + i);
    ushort4 oh, ol;
    unsigned short* ph = reinterpret_cast<unsigned short*>(&oh);
    unsigned short* pl = reinterpret_cast<unsigned short*>(&ol);
#pragma unroll
    for (int j = 0; j < 4; ++j) {
      float f = acc[i][j] + bb[j];
      unsigned short h = f2bf(f);
      ph[j] = h;
      pl[j] = f2bf(f - bf2f(h));
    }
    *reinterpret_cast<ushort4*>(&xhi[rowi*DK + col0 + tc*4]) = oh;
    *reinterpret_cast<ushort4*>(&xlo[rowi*DK + col0 + tc*4]) = ol;
  }
}

// ---------------------------------------------------------------------------
// K2: split-bf16 MFMA GEMM (3-pass: xh*Wh + xh*Wl + xl*Wh) + fused gate math
// + fused 128-step chunk scan. BM=128 rows (one chunk), 256 tile cols =
// 128 h/g channel pairs. 4 waves, each 128 rows x 64 cols (8m x 4n frags).
// Staging via global_load_lds (zero staging VGPRs, m97 2-barrier structure).
// LDS layout identical to round-3 proven kernel: pre-swizzled global source,
// linear LDS write i*1024 + lane*16 == r*64 + s*16.
// ---------------------------------------------------------------------------
__global__ __launch_bounds__(256, 2) void hg_mfma_scan(
    const unsigned short* __restrict__ xhi, const unsigned short* __restrict__ xlo,
    const unsigned short* __restrict__ wthi, const unsigned short* __restrict__ wtlo,
    float* __restrict__ chP, float* __restrict__ chL)
{
  __shared__ char smem[49152];   // Ah 8K | Al 8K | Bh 16K | Bl 16K
  const int t = threadIdx.x;
  const int row0 = blockIdx.x * 128;
  const int colbase = blockIdx.y * 128;   // channel base (128 channels/block)

  const int w = t >> 6;        // wave 0..3
  const int l = t & 63;

  // --- per-lane global source pointers for this wave's 12 tile-loads ---
  // Global load index i = w*12 + q, i in 0..47:
  //   i 0..7   : Ah rows  r = i*16 + (l>>2)
  //   i 8..15  : Al rows  (i-8)
  //   i 16..31 : Bh cols  c = (i-16)*16 + (l>>2)
  //   i 32..47 : Bl cols  (i-32)
  // LDS dest (HW): smem + i*1024 + l*16  == region + r(c)*64 + s*16
  const unsigned short* srcp[12];
#pragma unroll
  for (int q = 0; q < 12; ++q) {
    int i = w*12 + q;
    const unsigned short* base;
    size_t off;
    if (i < 16) {
      int ii = i & 7;
      int r = ii*16 + (l >> 2), s = l & 3;
      int slog = s ^ ((r >> 1) & 3);
      base = (i < 8) ? xhi : xlo;
      off = (size_t)(row0 + r)*DK + slog*8;
    } else {
      int ii = (i - 16) & 15;
      int c = ii*16 + (l >> 2), s = l & 3;
      int slog = s ^ ((c >> 1) & 3);
      int grp = c >> 4, u = c & 15;
      int wr = ((grp & 1) ? DIEXP : 0) + colbase + (grp >> 1)*16 + u;
      base = (i < 32) ? wthi : wtlo;
      off = (size_t)wr*DK + slog*8;
    }
    srcp[q] = base + off;
  }

  // --- fragment read maps (unchanged from proven round-3 kernel) ---
  const int u  = l & 15;
  const int qh = l >> 4;
  const int phys = qh ^ ((u >> 1) & 3);
  const int aoff_h = u*64 + phys*16;                      // + m*1024
  const int aoff_l = 8192 + aoff_h;
  const int boff_h = 16384 + (w*64 + u)*64 + phys*16;     // + n*1024
  const int boff_l = 16384 + boff_h;

  f32x4 acc[8][4];
#pragma unroll
  for (int m = 0; m < 8; ++m)
#pragma unroll
    for (int n = 0; n < 4; ++n)
      acc[m][n] = (f32x4){0.f, 0.f, 0.f, 0.f};

#pragma unroll 1
  for (int kt = 0; kt < DK/32; ++kt) {
    // stage tile kt: 12 direct global->LDS loads per wave (wave-uniform dest)
#pragma unroll
    for (int q = 0; q < 12; ++q) {
      GL2LDS16(srcp[q] + kt*32, smem + (w*12 + q)*1024);
    }
    __syncthreads();            // drains vmcnt: tile visible
    short8 bh[4], bl[4];
#pragma unroll
    for (int n = 0; n < 4; ++n) {
      bh[n] = *reinterpret_cast<const short8*>(smem + boff_h + n*1024);
      bl[n] = *reinterpret_cast<const short8*>(smem + boff_l + n*1024);
    }
#pragma unroll
    for (int m = 0; m < 8; ++m) {
      short8 ah = *reinterpret_cast<const short8*>(smem + aoff_h + m*1024);
      short8 al = *reinterpret_cast<const short8*>(smem + aoff_l + m*1024);
#pragma unroll
      for (int n = 0; n < 4; ++n) {
        acc[m][n] = __builtin_amdgcn_mfma_f32_16x16x32_bf16(ah, bh[n], acc[m][n], 0, 0, 0);
        acc[m][n] = __builtin_amdgcn_mfma_f32_16x16x32_bf16(ah, bl[n], acc[m][n], 0, 0, 0);
        acc[m][n] = __builtin_amdgcn_mfma_f32_16x16x32_bf16(al, bh[n], acc[m][n], 0, 0, 0);
      }
    }
    __syncthreads();            // all reads done before next overwrite
  }

  // ---- fused gate math + chunk scan (wave-local: 128 rows x 32 channels) ----
  float* segP = reinterpret_cast<float*>(smem);            // 16 KB
  float* segV = reinterpret_cast<float*>(smem + 16384);    // 16 KB
  // C/D layout: col = lane&15, row = (lane>>4)*4 + reg. Lane's 4 regs are
  // 4 consecutive timesteps -> per-lane 4-step segment summary.
#pragma unroll
  for (int p = 0; p < 2; ++p) {        // channel pair group (n=2p:h, 2p+1:g)
#pragma unroll
    for (int m = 0; m < 8; ++m) {
      float P = 0.f, V = -INFINITY;
#pragma unroll
      for (int r = 0; r < 4; ++r) {
        float lcv, lvv;
        gate_math(acc[m][2*p+1][r], acc[m][2*p][r], lcv, lvv);  // (g, h)
        V = lax(lcv, V, lvv);
        P += lcv;
      }
      int sidx = w*1024 + ((m*4 + qh)*2 + p)*16 + u;
      segP[sidx] = P;
      segV[sidx] = V;
    }
  }
  __syncthreads();
  if (l < 32) {                        // 32 channels per wave
    int p = l >> 4, uu = l & 15;
    float Pa = 0.f, Va = -INFINITY;
#pragma unroll
    for (int mm = 0; mm < 8; ++mm)     // time order: m major, hi minor
#pragma unroll
      for (int hh = 0; hh < 4; ++hh) {
        int sidx = w*1024 + ((mm*4 + hh)*2 + p)*16 + uu;
        float Ps = segP[sidx], Vs = segV[sidx];
        Va = lax(Ps, Va, Vs);
        Pa += Ps;
      }
    int b = row0 >> 12;                // row0 / 4096
    int c = (row0 & 4095) >> 7;        // chunk within sequence
    int j = colbase + 32*w + p*16 + uu;
    size_t o = ((size_t)(b*CCH + c))*DIEXP + j;
    chP[o] = Pa;
    chL[o] = Va;
  }
}

// ---------------------------------------------------------------------------
// Fallback path (round-2, proven): fp32 x + VALU GEMM + fused scan
// ---------------------------------------------------------------------------
__global__ __launch_bounds__(256) void emb_gemm(
    const float* __restrict__ obs, const float* __restrict__ Wemb,
    const float* __restrict__ bemb, float* __restrict__ x)
{
  __shared__ float As[16][132];
  __shared__ float Bs[16][64];
  const int tid = threadIdx.x;
  const int tr = tid >> 4, tc = tid & 15;
  const int row0 = blockIdx.x * 128;
  const int col0 = blockIdx.y * 64;
  float acc[8][4] = {};
  for (int kt = 0; kt < DIN/16; ++kt) {
    float4 av[2];
#pragma unroll
    for (int r = 0; r < 2; ++r) {
      int idx = tid + 256*r;
      int m = idx >> 2, k4 = idx & 3;
      av[r] = *reinterpret_cast<const float4*>(
          &obs[(size_t)(row0+m)*DIN + kt*16 + k4*4]);
    }
    int bk = tid >> 4;
    int bc = (tid & 15) * 4;
    float4 bv = *reinterpret_cast<const float4*>(
        &Wemb[(size_t)(kt*16+bk)*DK + col0 + bc]);
    __syncthreads();
#pragma unroll
    for (int r = 0; r < 2; ++r) {
      int idx = tid + 256*r;
      int m = idx >> 2, k4 = idx & 3;
      As[k4*4+0][m] = av[r].x;
      As[k4*4+1][m] = av[r].y;
      As[k4*4+2][m] = av[r].z;
      As[k4*4+3][m] = av[r].w;
    }
    *reinterpret_cast<float4*>(&Bs[bk][bc]) = bv;
    __syncthreads();
#pragma unroll
    for (int k = 0; k < 16; ++k) {
      float4 a0 = *reinterpret_cast<const float4*>(&As[k][tr*8]);
      float4 a1 = *reinterpret_cast<const float4*>(&As[k][tr*8+4]);
      float4 b0 = *reinterpret_cast<const float4*>(&Bs[k][tc*4]);
      float ar[8] = {a0.x,a0.y,a0.z,a0.w,a1.x,a1.y,a1.z,a1.w};
      float br[4] = {b0.x,b0.y,b0.z,b0.w};
#pragma unroll
      for (int i = 0; i < 8; ++i)
#pragma unroll
        for (int j = 0; j < 4; ++j)
          acc[i][j] = fmaf(ar[i], br[j], acc[i][j]);
    }
  }
  float4 bias = *reinterpret_cast<const float4*>(&bemb[col0 + tc*4]);
#pragma unroll
  for (int i = 0; i < 8; ++i) {
    float4 o;
    o.x = acc[i][0] + bias.x; o.y = acc[i][1] + bias.y;
    o.z = acc[i][2] + bias.z; o.w = acc[i][3] + bias.w;
    *reinterpret_cast<float4*>(
        &x[(size_t)(row0 + tr*8 + i)*DK + col0 + tc*4]) = o;
  }
}

__global__ __launch_bounds__(256) void hg_gemm_scan(
    const float* __restrict__ x, const float* __restrict__ Whg,
    float* __restrict__ chP, float* __restrict__ chL)
{
  __shared__ float As[16][132];
  __shared__ float Bs[16][128];
  const int tid = threadIdx.x;
  const int tr = tid >> 4, tc = tid & 15;
  const int row0 = blockIdx.x * 128;
  const int col0 = blockIdx.y * 64;
  float acch[8][4] = {};
  float accg[8][4] = {};
  for (int kt = 0; kt < DK/16; ++kt) {
    float4 av[2];
#pragma unroll
    for (int r = 0; r < 2; ++r) {
      int idx = tid + 256*r;
      int m = idx >> 2, k4 = idx & 3;
      av[r] = *reinterpret_cast<const float4*>(
          &x[(size_t)(row0+m)*DK + kt*16 + k4*4]);
    }
    float4 bv[2];
#pragma unroll
    for (int r = 0; r < 2; ++r) {
      int idx = tid + 256*r;
      int k = idx >> 5;
      int c4 = idx & 31;
      int col = (c4 < 16) ? (col0 + c4*4) : (DIEXP + col0 + (c4-16)*4);
      bv[r] = *reinterpret_cast<const float4*>(
          &Whg[(size_t)(kt*16+k)*NHG + col]);
    }
    __syncthreads();
#pragma unroll
    for (int r = 0; r < 2; ++r) {
      int idx = tid + 256*r;
      int m = idx >> 2, k4 = idx & 3;
      As[k4*4+0][m] = av[r].x;
      As[k4*4+1][m] = av[r].y;
      As[k4*4+2][m] = av[r].z;
      As[k4*4+3][m] = av[r].w;
    }
#pragma unroll
    for (int r = 0; r < 2; ++r) {
      int idx = tid + 256*r;
      int k = idx >> 5;
      int c4 = idx & 31;
      int scol = (c4 < 16) ? c4*4 : (64 + (c4-16)*4);
      *reinterpret_cast<float4*>(&Bs[k][scol]) = bv[r];
    }
    __syncthreads();
#pragma unroll
    for (int k = 0; k < 16; ++k) {
      float4 a0 = *reinterpret_cast<const float4*>(&As[k][tr*8]);
      float4 a1 = *reinterpret_cast<const float4*>(&As[k][tr*8+4]);
      float4 bh = *reinterpret_cast<const float4*>(&Bs[k][tc*4]);
      float4 bg = *reinterpret_cast<const float4*>(&Bs[k][64 + tc*4]);
      float ar[8] = {a0.x,a0.y,a0.z,a0.w,a1.x,a1.y,a1.z,a1.w};
      float bhr[4] = {bh.x,bh.y,bh.z,bh.w};
      float bgr[4] = {bg.x,bg.y,bg.z,bg.w};
#pragma unroll
      for (int i = 0; i < 8; ++i) {
#pragma unroll
        for (int j = 0; j < 4; ++j) {
          acch[i][j] = fmaf(ar[i], bhr[j], acch[i][j]);
          accg[i][j] = fmaf(ar[i], bgr[j], accg[i][j]);
        }
      }
    }
  }
  float P[4], V[4];
#pragma unroll
  for (int j = 0; j < 4; ++j) { P[j] = 0.f; V[j] = -INFINITY; }
#pragma unroll
  for (int i = 0; i < 8; ++i) {
#pragma unroll
    for (int j = 0; j < 4; ++j) {
      float lcv, lvv;
      gate_math(accg[i][j], acch[i][j], lcv, lvv);
      V[j] = lax(lcv, V[j], lvv);
      P[j] += lcv;
    }
  }
  __syncthreads();
#pragma unroll
  for (int j = 0; j < 4; ++j) {
    As[tr][tc*4+j] = P[j];
    Bs[tr][tc*4+j] = V[j];
  }
  __syncthreads();
  if (tid < 64) {
    float Pa = 0.f, Va = -INFINITY;
#pragma unroll
    for (int t2 = 0; t2 < 16; ++t2) {
      float Pc = As[t2][tid], Vc = Bs[t2][tid];
      Va = lax(Pc, Va, Vc);
      Pa += Pc;
    }
    int b = row0 / SS;
    int c = (row0 % SS) / TCH;
    size_t o = ((size_t)(b*CCH + c))*DIEXP + col0 + tid;
    chP[o] = Pa;
    chL[o] = Va;
  }
}

// ---------------------------------------------------------------------------
// K3: combine chunk summaries; K4: out = h_last @ W_out
// ---------------------------------------------------------------------------
__global__ __launch_bounds__(256) void combine_chunks(
    const float* __restrict__ chP, const float* __restrict__ chL,
    float* __restrict__ hl)
{
  int ch = blockIdx.x*256 + threadIdx.x;
  int b = ch / DIEXP, i = ch % DIEXP;
  float L = -INFINITY;
#pragma unroll
  for (int c = 0; c < CCH; ++c) {
    size_t o = ((size_t)(b*CCH + c))*DIEXP + i;
    L = lax(chP[o], L, chL[o]);
  }
  hl[ch] = __expf(L);
}

__global__ __launch_bounds__(512) void out_gemm(
    const float* __restrict__ hl, const float* __restrict__ Wout,
    float* __restrict__ out)
{
  __shared__ float hs[DIEXP];
  int b = blockIdx.x;
  for (int i = threadIdx.x; i < DIEXP; i += 512) hs[i] = hl[b*DIEXP + i];
  __syncthreads();
  int d = threadIdx.x;
  float s = 0.f;
#pragma unroll 8
  for (int i = 0; i < DIEXP; ++i)
    s = fmaf(hs[i], Wout[(size_t)i*DK + d], s);
  out[(size_t)b*DK + d] = s;
}

// ---------------------------------------------------------------------------
extern "C" void kernel_launch(void* const* d_in, const int* in_sizes, int n_in,
                              void* d_out, int out_size, void* d_ws, size_t ws_size,
                              hipStream_t stream) {
  const float* obs  = (const float*)d_in[0];
  const float* Wemb = (const float*)d_in[1];
  const float* bemb = (const float*)d_in[2];
  const float* Whg  = (const float*)d_in[3];
  const float* Wout = (const float*)d_in[4];
  float* out = (float*)d_out;

  char* ws = (char*)d_ws;
  float* chP = (float*)ws;                                  // 1,572,864 B
  float* chL = (float*)(ws + 1572864);                      // 1,572,864 B
  float* hl  = (float*)(ws + 3145728);                      //    49,152 B
  // new path:
  unsigned short* wthi = (unsigned short*)(ws + 3194880);   // 1,572,864 B
  unsigned short* wtlo = (unsigned short*)(ws + 4767744);   // 1,572,864 B
  unsigned short* xhi  = (unsigned short*)(ws + 6340608);   // 67,108,864 B
  unsigned short* xlo  = (unsigned short*)(ws + 73449472);  // 67,108,864 B
  const size_t needNew = 140558336;
  // fallback:
  float* xf = (float*)(ws + 3194880);                       // 134,217,728 B
  const size_t needOld = 137412608;

  if (ws_size >= needNew) {
    wsplit<<<dim3(NHG), 256, 0, stream>>>(Whg, wthi, wtlo);
    emb_gemm_bf<<<dim3(MROWS/128, DK/64), 256, 0, stream>>>(obs, Wemb, bemb, xhi, xlo);
    hg_mfma_scan<<<dim3(MROWS/128, DIEXP/128), 256, 0, stream>>>(
        xhi, xlo, wthi, wtlo, chP, chL);
  } else if (ws_size >= needOld) {
    emb_gemm<<<dim3(MROWS/128, DK/64), 256, 0, stream>>>(obs, Wemb, bemb, xf);
    hg_gemm_scan<<<dim3(MROWS/128, DIEXP/64), 256, 0, stream>>>(xf, Whg, chP, chL);
  }
  combine_chunks<<<dim3(NCHAN/256), 256, 0, stream>>>(chP, chL, hl);
  out_gemm<<<dim3(NB), 512, 0, stream>>>(hl, Wout, out);
}

// Round 5
// 300.170 us; speedup vs baseline: 4.6960x; 1.6119x over previous
//
#include <hip/hip_runtime.h>
#include <cstdint>
#include <cstddef>
#include <math.h>

// Problem dims
#define NB    16
#define SS    4096
#define DIN   64
#define DK    512
#define DIEXP 768
#define MROWS (NB*SS)      // 65536
#define NHG   (2*DIEXP)    // 1536
#define CCH   32           // chunks per sequence (chunk len 128)
#define TCH   128
#define NCHAN (NB*DIEXP)   // 12288

typedef __attribute__((ext_vector_type(8))) _Float16 half8;  // 8 fp16 (4 VGPRs)
typedef __attribute__((ext_vector_type(4))) float f32x4;

#define GL2LDS16(g, lp) \
  __builtin_amdgcn_global_load_lds( \
      (const __attribute__((address_space(1))) void*)(g), \
      (__attribute__((address_space(3))) void*)(lp), 16, 0, 0)

__device__ __forceinline__ unsigned short f2h(float f) {
  _Float16 h = (_Float16)f;            // v_cvt_f16_f32, RNE
  return __builtin_bit_cast(unsigned short, h);
}

__device__ __forceinline__ float lax(float P, float L, float V) {
  // logaddexp(P + L, V); L may be -inf
  float xx = P + L;
  float m  = fmaxf(xx, V);
  float d  = fminf(xx, V) - m;
  return m + __logf(1.f + __expf(d));
}

__device__ __forceinline__ void gate_math(float g, float h, float& lcv, float& lvv) {
  float spg  = fmaxf(g, 0.f) + __logf(1.f + __expf(-fabsf(g)));   // softplus(g)
  float logg = (h >= 0.f) ? __logf(h + 0.5f)
                          : (h - __logf(1.f + __expf(h)));        // log g(h)
  lcv = -spg;
  lvv = g - spg + logg;
}

// ---------------------------------------------------------------------------
// Pre-kernels: obs -> fp16; Wemb^T fp16; Whg^T fp16
// ---------------------------------------------------------------------------
__global__ __launch_bounds__(256) void obs2h(
    const float* __restrict__ obs, unsigned short* __restrict__ o16)
{
  size_t i = ((size_t)blockIdx.x*256 + threadIdx.x)*4;   // MROWS*DIN total
  float4 v = *reinterpret_cast<const float4*>(&obs[i]);
  ushort4 o;
  o.x = f2h(v.x); o.y = f2h(v.y); o.z = f2h(v.z); o.w = f2h(v.w);
  *reinterpret_cast<ushort4*>(&o16[i]) = o;
}

__global__ __launch_bounds__(64) void wembT16(
    const float* __restrict__ Wemb, unsigned short* __restrict__ wt)
{
  int n = blockIdx.x;                  // 0..511
  int k = threadIdx.x;                 // 0..63
  wt[n*DIN + k] = f2h(Wemb[(size_t)k*DK + n]);
}

__global__ __launch_bounds__(256) void wsplit16(
    const float* __restrict__ W, unsigned short* __restrict__ WT)
{
  int j = blockIdx.x;                  // 0..1535
  for (int k = threadIdx.x; k < DK; k += 256)
    WT[(size_t)j*DK + k] = f2h(W[(size_t)k*NHG + j]);
}

// ---------------------------------------------------------------------------
// K1: x16 = fp16(obs @ W_emb + b_emb). Single-shot K=64 MFMA tile.
// BM=128, BN=256, 4 waves. LDS: A[2][128r][32k] 16K | B[2][256c][32k] 32K.
// ---------------------------------------------------------------------------
__global__ __launch_bounds__(256, 2) void emb_mfma(
    const unsigned short* __restrict__ o16, const unsigned short* __restrict__ wembT,
    const float* __restrict__ bemb, unsigned short* __restrict__ x16)
{
  __shared__ char smem[49152];
  const int t = threadIdx.x;
  const int row0 = blockIdx.x * 128;
  const int col0 = blockIdx.y * 256;
  const int w = t >> 6, l = t & 63;

  // 48 chunks of 1KB: i 0..7 A kk0 | 8..15 A kk1 | 16..31 B kk0 | 32..47 B kk1
#pragma unroll
  for (int q = 0; q < 12; ++q) {
    int i = w*12 + q;
    int s = l & 3;
    const unsigned short* src;
    if (i < 16) {
      int kk = i >> 3, ii = i & 7;
      int r = ii*16 + (l >> 2);
      int slog = s ^ ((r >> 1) & 3);
      src = o16 + (size_t)(row0 + r)*DIN + kk*32 + slog*8;
    } else {
      int kk = (i - 16) >> 4, ii = (i - 16) & 15;
      int c = ii*16 + (l >> 2);
      int slog = s ^ ((c >> 1) & 3);
      src = wembT + (size_t)(col0 + c)*DIN + kk*32 + slog*8;
    }
    GL2LDS16(src, smem + i*1024);
  }
  __syncthreads();

  const int u  = l & 15;
  const int qh = l >> 4;
  const int phys = qh ^ ((u >> 1) & 3);
  const int aoff = u*64 + phys*16;
  const int boff = 16384 + (w*64 + u)*64 + phys*16;

  f32x4 acc[8][4];
#pragma unroll
  for (int m = 0; m < 8; ++m)
#pragma unroll
    for (int n = 0; n < 4; ++n)
      acc[m][n] = (f32x4){0.f, 0.f, 0.f, 0.f};

#pragma unroll
  for (int kk = 0; kk < 2; ++kk) {
    half8 b[4];
#pragma unroll
    for (int n = 0; n < 4; ++n)
      b[n] = *reinterpret_cast<const half8*>(smem + kk*16384 + boff + n*1024);
#pragma unroll
    for (int m = 0; m < 8; ++m) {
      half8 a = *reinterpret_cast<const half8*>(smem + kk*8192 + aoff + m*1024);
#pragma unroll
      for (int n = 0; n < 4; ++n)
        acc[m][n] = __builtin_amdgcn_mfma_f32_16x16x32_f16(a, b[n], acc[m][n], 0, 0, 0);
    }
  }

  float bias[4];
#pragma unroll
  for (int n = 0; n < 4; ++n) bias[n] = bemb[col0 + w*64 + n*16 + u];
#pragma unroll
  for (int m = 0; m < 8; ++m)
#pragma unroll
    for (int n = 0; n < 4; ++n) {
      int col = col0 + w*64 + n*16 + u;
#pragma unroll
      for (int r = 0; r < 4; ++r) {
        int row = row0 + m*16 + qh*4 + r;
        x16[(size_t)row*DK + col] = f2h(acc[m][n][r] + bias[n]);
      }
    }
}

// ---------------------------------------------------------------------------
// K2: single-pass fp16 MFMA GEMM + fused gate math + fused 128-step chunk
// scan. BM=128 rows (one chunk), 256 tile cols = 128 h/g channel pairs.
// 2-phase double-buffered: stage tile kt+1 BEFORE computing tile kt;
// one vmcnt-draining barrier per step. LDS: 2 x (A 8K | B 16K) = 48K.
// ---------------------------------------------------------------------------
__global__ __launch_bounds__(256, 2) void hg_mfma_scan(
    const unsigned short* __restrict__ x16, const unsigned short* __restrict__ wt16,
    float* __restrict__ chP, float* __restrict__ chL)
{
  __shared__ char smem[49152];
  const int t = threadIdx.x;
  const int row0 = blockIdx.x * 128;
  const int colbase = blockIdx.y * 128;   // channel base (128 channels/block)
  const int w = t >> 6, l = t & 63;

  // per-wave 6 staging chunks: i 0..7 = A rows, 8..23 = B cols (24 x 1KB)
  const unsigned short* srcp[6];
  int ldst[6];
#pragma unroll
  for (int q = 0; q < 6; ++q) {
    int i = w*6 + q;
    int s = l & 3;
    if (i < 8) {
      int r = i*16 + (l >> 2);
      int slog = s ^ ((r >> 1) & 3);
      srcp[q] = x16 + (size_t)(row0 + r)*DK + slog*8;
    } else {
      int c = (i - 8)*16 + (l >> 2);
      int slog = s ^ ((c >> 1) & 3);
      int grp = c >> 4, uu = c & 15;
      int wr = ((grp & 1) ? DIEXP : 0) + colbase + (grp >> 1)*16 + uu;
      srcp[q] = wt16 + (size_t)wr*DK + slog*8;
    }
    ldst[q] = i*1024;
  }

  // fragment read maps (proven round-3/4 layout; B base now 8192)
  const int u  = l & 15;
  const int qh = l >> 4;
  const int phys = qh ^ ((u >> 1) & 3);
  const int aoff = u*64 + phys*16;                   // + m*1024 + buf
  const int boff = 8192 + (w*64 + u)*64 + phys*16;   // + n*1024 + buf

  f32x4 acc[8][4];
#pragma unroll
  for (int m = 0; m < 8; ++m)
#pragma unroll
    for (int n = 0; n < 4; ++n)
      acc[m][n] = (f32x4){0.f, 0.f, 0.f, 0.f};

  // prologue: stage tile 0 into buf 0
#pragma unroll
  for (int q = 0; q < 6; ++q) GL2LDS16(srcp[q], smem + ldst[q]);
  __syncthreads();

  int cur = 0;
#pragma unroll 1
  for (int kt = 0; kt < DK/32; ++kt) {
    if (kt < DK/32 - 1) {              // stage NEXT tile into other buffer
      int nb = (cur ^ 1) * 24576;
#pragma unroll
      for (int q = 0; q < 6; ++q)
        GL2LDS16(srcp[q] + (kt + 1)*32, smem + nb + ldst[q]);
    }
    const char* bb = smem + cur*24576;
    half8 b[4];
#pragma unroll
    for (int n = 0; n < 4; ++n)
      b[n] = *reinterpret_cast<const half8*>(bb + boff + n*1024);
#pragma unroll
    for (int m = 0; m < 8; ++m) {
      half8 a = *reinterpret_cast<const half8*>(bb + aoff + m*1024);
#pragma unroll
      for (int n = 0; n < 4; ++n)
        acc[m][n] = __builtin_amdgcn_mfma_f32_16x16x32_f16(a, b[n], acc[m][n], 0, 0, 0);
    }
    __syncthreads();                   // drains vmcnt: next tile ready,
    cur ^= 1;                          // current buffer reads complete
  }

  // ---- fused gate math + chunk scan (wave-local: 128 rows x 32 channels) ----
  float* segP = reinterpret_cast<float*>(smem);            // 16 KB
  float* segV = reinterpret_cast<float*>(smem + 16384);    // 16 KB
  // C/D layout: col = lane&15, row = (lane>>4)*4 + reg. Lane's 4 regs are
  // 4 consecutive timesteps -> per-lane 4-step segment summary.
#pragma unroll
  for (int p = 0; p < 2; ++p) {        // channel pair group (n=2p:h, 2p+1:g)
#pragma unroll
    for (int m = 0; m < 8; ++m) {
      float P = 0.f, V = -INFINITY;
#pragma unroll
      for (int r = 0; r < 4; ++r) {
        float lcv, lvv;
        gate_math(acc[m][2*p+1][r], acc[m][2*p][r], lcv, lvv);  // (g, h)
        V = lax(lcv, V, lvv);
        P += lcv;
      }
      int sidx = w*1024 + ((m*4 + qh)*2 + p)*16 + u;
      segP[sidx] = P;
      segV[sidx] = V;
    }
  }
  __syncthreads();
  if (l < 32) {                        // 32 channels per wave
    int p = l >> 4, uu = l & 15;
    float Pa = 0.f, Va = -INFINITY;
#pragma unroll
    for (int mm = 0; mm < 8; ++mm)     // time order: m major, hi minor
#pragma unroll
      for (int hh = 0; hh < 4; ++hh) {
        int sidx = w*1024 + ((mm*4 + hh)*2 + p)*16 + uu;
        float Ps = segP[sidx], Vs = segV[sidx];
        Va = lax(Ps, Va, Vs);
        Pa += Ps;
      }
    int b = row0 >> 12;                // row0 / 4096
    int c = (row0 & 4095) >> 7;        // chunk within sequence
    int j = colbase + 32*w + p*16 + uu;
    size_t o = ((size_t)(b*CCH + c))*DIEXP + j;
    chP[o] = Pa;
    chL[o] = Va;
  }
}

// ---------------------------------------------------------------------------
// Fallback path (round-2, proven): fp32 x + VALU GEMM + fused scan
// ---------------------------------------------------------------------------
__global__ __launch_bounds__(256) void emb_gemm(
    const float* __restrict__ obs, const float* __restrict__ Wemb,
    const float* __restrict__ bemb, float* __restrict__ x)
{
  __shared__ float As[16][132];
  __shared__ float Bs[16][64];
  const int tid = threadIdx.x;
  const int tr = tid >> 4, tc = tid & 15;
  const int row0 = blockIdx.x * 128;
  const int col0 = blockIdx.y * 64;
  float acc[8][4] = {};
  for (int kt = 0; kt < DIN/16; ++kt) {
    float4 av[2];
#pragma unroll
    for (int r = 0; r < 2; ++r) {
      int idx = tid + 256*r;
      int m = idx >> 2, k4 = idx & 3;
      av[r] = *reinterpret_cast<const float4*>(
          &obs[(size_t)(row0+m)*DIN + kt*16 + k4*4]);
    }
    int bk = tid >> 4;
    int bc = (tid & 15) * 4;
    float4 bv = *reinterpret_cast<const float4*>(
        &Wemb[(size_t)(kt*16+bk)*DK + col0 + bc]);
    __syncthreads();
#pragma unroll
    for (int r = 0; r < 2; ++r) {
      int idx = tid + 256*r;
      int m = idx >> 2, k4 = idx & 3;
      As[k4*4+0][m] = av[r].x;
      As[k4*4+1][m] = av[r].y;
      As[k4*4+2][m] = av[r].z;
      As[k4*4+3][m] = av[r].w;
    }
    *reinterpret_cast<float4*>(&Bs[bk][bc]) = bv;
    __syncthreads();
#pragma unroll
    for (int k = 0; k < 16; ++k) {
      float4 a0 = *reinterpret_cast<const float4*>(&As[k][tr*8]);
      float4 a1 = *reinterpret_cast<const float4*>(&As[k][tr*8+4]);
      float4 b0 = *reinterpret_cast<const float4*>(&Bs[k][tc*4]);
      float ar[8] = {a0.x,a0.y,a0.z,a0.w,a1.x,a1.y,a1.z,a1.w};
      float br[4] = {b0.x,b0.y,b0.z,b0.w};
#pragma unroll
      for (int i = 0; i < 8; ++i)
#pragma unroll
        for (int j = 0; j < 4; ++j)
          acc[i][j] = fmaf(ar[i], br[j], acc[i][j]);
    }
  }
  float4 bias = *reinterpret_cast<const float4*>(&bemb[col0 + tc*4]);
#pragma unroll
  for (int i = 0; i < 8; ++i) {
    float4 o;
    o.x = acc[i][0] + bias.x; o.y = acc[i][1] + bias.y;
    o.z = acc[i][2] + bias.z; o.w = acc[i][3] + bias.w;
    *reinterpret_cast<float4*>(
        &x[(size_t)(row0 + tr*8 + i)*DK + col0 + tc*4]) = o;
  }
}

__global__ __launch_bounds__(256) void hg_gemm_scan(
    const float* __restrict__ x, const float* __restrict__ Whg,
    float* __restrict__ chP, float* __restrict__ chL)
{
  __shared__ float As[16][132];
  __shared__ float Bs[16][128];
  const int tid = threadIdx.x;
  const int tr = tid >> 4, tc = tid & 15;
  const int row0 = blockIdx.x * 128;
  const int col0 = blockIdx.y * 64;
  float acch[8][4] = {};
  float accg[8][4] = {};
  for (int kt = 0; kt < DK/16; ++kt) {
    float4 av[2];
#pragma unroll
    for (int r = 0; r < 2; ++r) {
      int idx = tid + 256*r;
      int m = idx >> 2, k4 = idx & 3;
      av[r] = *reinterpret_cast<const float4*>(
          &x[(size_t)(row0+m)*DK + kt*16 + k4*4]);
    }
    float4 bv[2];
#pragma unroll
    for (int r = 0; r < 2; ++r) {
      int idx = tid + 256*r;
      int k = idx >> 5;
      int c4 = idx & 31;
      int col = (c4 < 16) ? (col0 + c4*4) : (DIEXP + col0 + (c4-16)*4);
      bv[r] = *reinterpret_cast<const float4*>(
          &Whg[(size_t)(kt*16+k)*NHG + col]);
    }
    __syncthreads();
#pragma unroll
    for (int r = 0; r < 2; ++r) {
      int idx = tid + 256*r;
      int m = idx >> 2, k4 = idx & 3;
      As[k4*4+0][m] = av[r].x;
      As[k4*4+1][m] = av[r].y;
      As[k4*4+2][m] = av[r].z;
      As[k4*4+3][m] = av[r].w;
    }
#pragma unroll
    for (int r = 0; r < 2; ++r) {
      int idx = tid + 256*r;
      int k = idx >> 5;
      int c4 = idx & 31;
      int scol = (c4 < 16) ? c4*4 : (64 + (c4-16)*4);
      *reinterpret_cast<float4*>(&Bs[k][scol]) = bv[r];
    }
    __syncthreads();
#pragma unroll
    for (int k = 0; k < 16; ++k) {
      float4 a0 = *reinterpret_cast<const float4*>(&As[k][tr*8]);
      float4 a1 = *reinterpret_cast<const float4*>(&As[k][tr*8+4]);
      float4 bh = *reinterpret_cast<const float4*>(&Bs[k][tc*4]);
      float4 bg = *reinterpret_cast<const float4*>(&Bs[k][64 + tc*4]);
      float ar[8] = {a0.x,a0.y,a0.z,a0.w,a1.x,a1.y,a1.z,a1.w};
      float bhr[4] = {bh.x,bh.y,bh.z,bh.w};
      float bgr[4] = {bg.x,bg.y,bg.z,bg.w};
#pragma unroll
      for (int i = 0; i < 8; ++i) {
#pragma unroll
        for (int j = 0; j < 4; ++j) {
          acch[i][j] = fmaf(ar[i], bhr[j], acch[i][j]);
          accg[i][j] = fmaf(ar[i], bgr[j], accg[i][j]);
        }
      }
    }
  }
  float P[4], V[4];
#pragma unroll
  for (int j = 0; j < 4; ++j) { P[j] = 0.f; V[j] = -INFINITY; }
#pragma unroll
  for (int i = 0; i < 8; ++i) {
#pragma unroll
    for (int j = 0; j < 4; ++j) {
      float lcv, lvv;
      gate_math(accg[i][j], acch[i][j], lcv, lvv);
      V[j] = lax(lcv, V[j], lvv);
      P[j] += lcv;
    }
  }
  __syncthreads();
#pragma unroll
  for (int j = 0; j < 4; ++j) {
    As[tr][tc*4+j] = P[j];
    Bs[tr][tc*4+j] = V[j];
  }
  __syncthreads();
  if (tid < 64) {
    float Pa = 0.f, Va = -INFINITY;
#pragma unroll
    for (int t2 = 0; t2 < 16; ++t2) {
      float Pc = As[t2][tid], Vc = Bs[t2][tid];
      Va = lax(Pc, Va, Vc);
      Pa += Pc;
    }
    int b = row0 / SS;
    int c = (row0 % SS) / TCH;
    size_t o = ((size_t)(b*CCH + c))*DIEXP + col0 + tid;
    chP[o] = Pa;
    chL[o] = Va;
  }
}

// ---------------------------------------------------------------------------
// K3: combine chunk summaries; K4: out = h_last @ W_out
// ---------------------------------------------------------------------------
__global__ __launch_bounds__(256) void combine_chunks(
    const float* __restrict__ chP, const float* __restrict__ chL,
    float* __restrict__ hl)
{
  int ch = blockIdx.x*256 + threadIdx.x;
  int b = ch / DIEXP, i = ch % DIEXP;
  float L = -INFINITY;
#pragma unroll
  for (int c = 0; c < CCH; ++c) {
    size_t o = ((size_t)(b*CCH + c))*DIEXP + i;
    L = lax(chP[o], L, chL[o]);
  }
  hl[ch] = __expf(L);
}

__global__ __launch_bounds__(512) void out_gemm(
    const float* __restrict__ hl, const float* __restrict__ Wout,
    float* __restrict__ out)
{
  __shared__ float hs[DIEXP];
  int b = blockIdx.x;
  for (int i = threadIdx.x; i < DIEXP; i += 512) hs[i] = hl[b*DIEXP + i];
  __syncthreads();
  int d = threadIdx.x;
  float s = 0.f;
#pragma unroll 8
  for (int i = 0; i < DIEXP; ++i)
    s = fmaf(hs[i], Wout[(size_t)i*DK + d], s);
  out[(size_t)b*DK + d] = s;
}

// ---------------------------------------------------------------------------
extern "C" void kernel_launch(void* const* d_in, const int* in_sizes, int n_in,
                              void* d_out, int out_size, void* d_ws, size_t ws_size,
                              hipStream_t stream) {
  const float* obs  = (const float*)d_in[0];
  const float* Wemb = (const float*)d_in[1];
  const float* bemb = (const float*)d_in[2];
  const float* Whg  = (const float*)d_in[3];
  const float* Wout = (const float*)d_in[4];
  float* out = (float*)d_out;

  char* ws = (char*)d_ws;
  float* chP = (float*)ws;                                  // 1,572,864 B
  float* chL = (float*)(ws + 1572864);                      // 1,572,864 B
  float* hl  = (float*)(ws + 3145728);                      //    49,152 B
  // fp16 path:
  unsigned short* wt16   = (unsigned short*)(ws + 3194880); // 1,572,864 B
  unsigned short* wembT  = (unsigned short*)(ws + 4767744); //    65,536 B
  unsigned short* o16    = (unsigned short*)(ws + 4833280); // 8,388,608 B
  unsigned short* x16    = (unsigned short*)(ws + 13221888);// 67,108,864 B
  const size_t needNew = 80330752;
  // fallback:
  float* xf = (float*)(ws + 3194880);                       // 134,217,728 B
  const size_t needOld = 137412608;

  if (ws_size >= needNew) {
    obs2h<<<dim3(MROWS*DIN/1024), 256, 0, stream>>>(obs, o16);
    wembT16<<<dim3(DK), 64, 0, stream>>>(Wemb, wembT);
    wsplit16<<<dim3(NHG), 256, 0, stream>>>(Whg, wt16);
    emb_mfma<<<dim3(MROWS/128, DK/256), 256, 0, stream>>>(o16, wembT, bemb, x16);
    hg_mfma_scan<<<dim3(MROWS/128, DIEXP/128), 256, 0, stream>>>(
        x16, wt16, chP, chL);
  } else if (ws_size >= needOld) {
    emb_gemm<<<dim3(MROWS/128, DK/64), 256, 0, stream>>>(obs, Wemb, bemb, xf);
    hg_gemm_scan<<<dim3(MROWS/128, DIEXP/64), 256, 0, stream>>>(xf, Whg, chP, chL);
  }
  combine_chunks<<<dim3(NCHAN/256), 256, 0, stream>>>(chP, chL, hl);
  out_gemm<<<dim3(NB), 512, 0, stream>>>(hl, Wout, out);
}

// Round 6
// 209.079 us; speedup vs baseline: 6.7419x; 1.4357x over previous
//
#include <hip/hip_runtime.h>
#include <cstdint>
#include <cstddef>
#include <math.h>

// Problem dims
#define NB    16
#define SS    4096
#define DIN   64
#define DK    512
#define DIEXP 768
#define MROWS (NB*SS)      // 65536
#define NHG   (2*DIEXP)    // 1536
#define CCH   32           // chunks per sequence (chunk len 128)
#define TCH   128
#define NCHAN (NB*DIEXP)   // 12288

typedef __attribute__((ext_vector_type(8))) _Float16 half8;  // 8 fp16 (4 VGPRs)
typedef __attribute__((ext_vector_type(4))) float f32x4;

#define GL2LDS16(g, lp) \
  __builtin_amdgcn_global_load_lds( \
      (const __attribute__((address_space(1))) void*)(g), \
      (__attribute__((address_space(3))) void*)(lp), 16, 0, 0)

__device__ __forceinline__ unsigned short f2h(float f) {
  _Float16 h = (_Float16)f;            // v_cvt_f16_f32, RNE
  return __builtin_bit_cast(unsigned short, h);
}

// log-space helpers (fallback path only)
__device__ __forceinline__ float lax(float P, float L, float V) {
  float xx = P + L;
  float m  = fmaxf(xx, V);
  float d  = fminf(xx, V) - m;
  return m + __logf(1.f + __expf(d));
}
__device__ __forceinline__ void gate_math(float g, float h, float& lcv, float& lvv) {
  float spg  = fmaxf(g, 0.f) + __logf(1.f + __expf(-fabsf(g)));
  float logg = (h >= 0.f) ? __logf(h + 0.5f)
                          : (h - __logf(1.f + __expf(h)));
  lcv = -spg;
  lvv = g - spg + logg;
}

// ---------------------------------------------------------------------------
// Pre-kernels: obs -> fp16; Wemb^T fp16; Whg^T fp16
// ---------------------------------------------------------------------------
__global__ __launch_bounds__(256) void obs2h(
    const float* __restrict__ obs, unsigned short* __restrict__ o16)
{
  size_t i = ((size_t)blockIdx.x*256 + threadIdx.x)*4;   // MROWS*DIN total
  float4 v = *reinterpret_cast<const float4*>(&obs[i]);
  ushort4 o;
  o.x = f2h(v.x); o.y = f2h(v.y); o.z = f2h(v.z); o.w = f2h(v.w);
  *reinterpret_cast<ushort4*>(&o16[i]) = o;
}

__global__ __launch_bounds__(64) void wembT16(
    const float* __restrict__ Wemb, unsigned short* __restrict__ wt)
{
  int n = blockIdx.x;                  // 0..511
  int k = threadIdx.x;                 // 0..63
  wt[n*DIN + k] = f2h(Wemb[(size_t)k*DK + n]);
}

__global__ __launch_bounds__(256) void wsplit16(
    const float* __restrict__ W, unsigned short* __restrict__ WT)
{
  int j = blockIdx.x;                  // 0..1535
  for (int k = threadIdx.x; k < DK; k += 256)
    WT[(size_t)j*DK + k] = f2h(W[(size_t)k*NHG + j]);
}

// ---------------------------------------------------------------------------
// K1: x16 = fp16(obs @ W_emb + b_emb). Single-shot K=64 MFMA tile.
// ---------------------------------------------------------------------------
__global__ __launch_bounds__(256, 2) void emb_mfma(
    const unsigned short* __restrict__ o16, const unsigned short* __restrict__ wembT,
    const float* __restrict__ bemb, unsigned short* __restrict__ x16)
{
  __shared__ char smem[49152];
  const int t = threadIdx.x;
  const int row0 = blockIdx.x * 128;
  const int col0 = blockIdx.y * 256;
  const int w = t >> 6, l = t & 63;

#pragma unroll
  for (int q = 0; q < 12; ++q) {
    int i = w*12 + q;
    int s = l & 3;
    const unsigned short* src;
    if (i < 16) {
      int kk = i >> 3, ii = i & 7;
      int r = ii*16 + (l >> 2);
      int slog = s ^ ((r >> 1) & 3);
      src = o16 + (size_t)(row0 + r)*DIN + kk*32 + slog*8;
    } else {
      int kk = (i - 16) >> 4, ii = (i - 16) & 15;
      int c = ii*16 + (l >> 2);
      int slog = s ^ ((c >> 1) & 3);
      src = wembT + (size_t)(col0 + c)*DIN + kk*32 + slog*8;
    }
    GL2LDS16(src, smem + i*1024);
  }
  __syncthreads();

  const int u  = l & 15;
  const int qh = l >> 4;
  const int phys = qh ^ ((u >> 1) & 3);
  const int aoff = u*64 + phys*16;
  const int boff = 16384 + (w*64 + u)*64 + phys*16;

  f32x4 acc[8][4];
#pragma unroll
  for (int m = 0; m < 8; ++m)
#pragma unroll
    for (int n = 0; n < 4; ++n)
      acc[m][n] = (f32x4){0.f, 0.f, 0.f, 0.f};

#pragma unroll
  for (int kk = 0; kk < 2; ++kk) {
    half8 b[4];
#pragma unroll
    for (int n = 0; n < 4; ++n)
      b[n] = *reinterpret_cast<const half8*>(smem + kk*16384 + boff + n*1024);
#pragma unroll
    for (int m = 0; m < 8; ++m) {
      half8 a = *reinterpret_cast<const half8*>(smem + kk*8192 + aoff + m*1024);
#pragma unroll
      for (int n = 0; n < 4; ++n)
        acc[m][n] = __builtin_amdgcn_mfma_f32_16x16x32_f16(a, b[n], acc[m][n], 0, 0, 0);
    }
  }

  float bias[4];
#pragma unroll
  for (int n = 0; n < 4; ++n) bias[n] = bemb[col0 + w*64 + n*16 + u];
#pragma unroll
  for (int m = 0; m < 8; ++m)
#pragma unroll
    for (int n = 0; n < 4; ++n) {
      int col = col0 + w*64 + n*16 + u;
#pragma unroll
      for (int r = 0; r < 4; ++r) {
        int row = row0 + m*16 + qh*4 + r;
        x16[(size_t)row*DK + col] = f2h(acc[m][n][r] + bias[n]);
      }
    }
}

// ---------------------------------------------------------------------------
// K2: fp16 MFMA GEMM + fused LINEAR-space gate math + 128-step chunk scan.
// 3-buffer pipeline, counted vmcnt(12): 2 tiles in flight across barriers.
// Per K-step: [lgkm0; barrier] [issue kt+2 -> freed buf] [vmcnt(12); barrier]
// [ds_read + 32 MFMA (setprio 1)].
// Chunk summary per channel: (A = prod a_t, V = scanned h) with
// a = sigmoid(-gate), b = sigmoid(gate)*g(hidden), h <- a*h + b.
// ---------------------------------------------------------------------------
__global__ __launch_bounds__(256, 2) void hg_mfma_scan(
    const unsigned short* __restrict__ x16, const unsigned short* __restrict__ wt16,
    float* __restrict__ chA, float* __restrict__ chV)
{
  __shared__ char smem[73728];            // 3 x 24 KB buffers
  const int t = threadIdx.x;
  const int row0 = blockIdx.x * 128;
  const int colbase = blockIdx.y * 128;   // channel base (128 channels/block)
  const int w = t >> 6, l = t & 63;

  // per-wave 6 staging chunks: i 0..7 = A rows, 8..23 = B cols (24 x 1KB)
  const unsigned short* srcp[6];
  int ldst[6];
#pragma unroll
  for (int q = 0; q < 6; ++q) {
    int i = w*6 + q;
    int s = l & 3;
    if (i < 8) {
      int r = i*16 + (l >> 2);
      int slog = s ^ ((r >> 1) & 3);
      srcp[q] = x16 + (size_t)(row0 + r)*DK + slog*8;
    } else {
      int c = (i - 8)*16 + (l >> 2);
      int slog = s ^ ((c >> 1) & 3);
      int grp = c >> 4, uu = c & 15;
      int wr = ((grp & 1) ? DIEXP : 0) + colbase + (grp >> 1)*16 + uu;
      srcp[q] = wt16 + (size_t)wr*DK + slog*8;
    }
    ldst[q] = i*1024;
  }

  // fragment read maps (proven layout; B region at +8192 within a buffer)
  const int u  = l & 15;
  const int qh = l >> 4;
  const int phys = qh ^ ((u >> 1) & 3);
  const int aoff = u*64 + phys*16;                   // + m*1024 + buf
  const int boff = 8192 + (w*64 + u)*64 + phys*16;   // + n*1024 + buf

  f32x4 acc[8][4];
#pragma unroll
  for (int m = 0; m < 8; ++m)
#pragma unroll
    for (int n = 0; n < 4; ++n)
      acc[m][n] = (f32x4){0.f, 0.f, 0.f, 0.f};

  // prologue: stage tiles 0 and 1
#pragma unroll
  for (int q = 0; q < 6; ++q) GL2LDS16(srcp[q],      smem +     0 + ldst[q]);
#pragma unroll
  for (int q = 0; q < 6; ++q) GL2LDS16(srcp[q] + 32, smem + 24576 + ldst[q]);
  int off_p = 49152, off_c = 0, off_n = 24576;   // p=free, c=tile kt, n=tile kt+1

#pragma unroll 1
  for (int kt = 0; kt < DK/32; ++kt) {
    asm volatile("s_waitcnt lgkmcnt(0)" ::: "memory");  // prev ds_reads retired
    __builtin_amdgcn_s_barrier();                       // off_p free everywhere
    if (kt < DK/32 - 2) {
#pragma unroll
      for (int q = 0; q < 6; ++q)
        GL2LDS16(srcp[q] + (kt + 2)*32, smem + off_p + ldst[q]);
      asm volatile("s_waitcnt vmcnt(12)" ::: "memory"); // tile kt landed
    } else if (kt == DK/32 - 2) {
      asm volatile("s_waitcnt vmcnt(6)" ::: "memory");
    } else {
      asm volatile("s_waitcnt vmcnt(0)" ::: "memory");
    }
    __builtin_amdgcn_s_barrier();                       // tile kt visible
    __builtin_amdgcn_sched_barrier(0);
    const char* bb = smem + off_c;
    half8 b[4];
#pragma unroll
    for (int n = 0; n < 4; ++n)
      b[n] = *reinterpret_cast<const half8*>(bb + boff + n*1024);
    __builtin_amdgcn_s_setprio(1);
#pragma unroll
    for (int m = 0; m < 8; ++m) {
      half8 a = *reinterpret_cast<const half8*>(bb + aoff + m*1024);
#pragma unroll
      for (int n = 0; n < 4; ++n)
        acc[m][n] = __builtin_amdgcn_mfma_f32_16x16x32_f16(a, b[n], acc[m][n], 0, 0, 0);
    }
    __builtin_amdgcn_s_setprio(0);
    int t0 = off_p; off_p = off_c; off_c = off_n; off_n = t0;
  }
  __syncthreads();              // loop fully done; overlay scratch on smem

  // ---- fused linear gate math + chunk scan (wave: 128 rows x 32 channels) ----
  float* segA = reinterpret_cast<float*>(smem);            // 16 KB
  float* segV = reinterpret_cast<float*>(smem + 16384);    // 16 KB
  // C/D layout: col = lane&15, row = (lane>>4)*4 + reg -> 4 consecutive
  // timesteps per lane; per-lane 4-step segment summary (A, V).
#pragma unroll
  for (int p = 0; p < 2; ++p) {        // channel pair (n=2p: hidden, 2p+1: gate)
#pragma unroll
    for (int m = 0; m < 8; ++m) {
      float A = 1.f, V = 0.f;
#pragma unroll
      for (int r = 0; r < 4; ++r) {
        float g = acc[m][2*p+1][r];
        float h = acc[m][2*p][r];
        float a  = __builtin_amdgcn_rcpf(1.f + __expf(g));    // sigmoid(-g) = 1-z
        float z  = 1.f - a;                                   // sigmoid(g)
        float sh = __builtin_amdgcn_rcpf(1.f + __expf(-h));   // sigmoid(h)
        float gv = (h >= 0.f) ? (h + 0.5f) : sh;              // g(h~)
        V = fmaf(a, V, z * gv);
        A *= a;
      }
      int sidx = w*1024 + ((m*4 + qh)*2 + p)*16 + u;
      segA[sidx] = A;
      segV[sidx] = V;
    }
  }
  __syncthreads();
  if (l < 32) {                        // 32 channels per wave
    int p = l >> 4, uu = l & 15;
    float Aa = 1.f, Va = 0.f;
#pragma unroll
    for (int mm = 0; mm < 8; ++mm)     // time order: m major, qh minor
#pragma unroll
      for (int hh = 0; hh < 4; ++hh) {
        int sidx = w*1024 + ((mm*4 + hh)*2 + p)*16 + uu;
        float As = segA[sidx], Vs = segV[sidx];
        Va = fmaf(As, Va, Vs);
        Aa *= As;
      }
    int b = row0 >> 12;                // row0 / 4096
    int c = (row0 & 4095) >> 7;        // chunk within sequence
    int j = colbase + 32*w + p*16 + uu;
    size_t o = ((size_t)(b*CCH + c))*DIEXP + j;
    chA[o] = Aa;
    chV[o] = Va;
  }
}

// ---------------------------------------------------------------------------
// Fallback path (round-2, proven): fp32 x + VALU GEMM + log-space scan
// ---------------------------------------------------------------------------
__global__ __launch_bounds__(256) void emb_gemm(
    const float* __restrict__ obs, const float* __restrict__ Wemb,
    const float* __restrict__ bemb, float* __restrict__ x)
{
  __shared__ float As[16][132];
  __shared__ float Bs[16][64];
  const int tid = threadIdx.x;
  const int tr = tid >> 4, tc = tid & 15;
  const int row0 = blockIdx.x * 128;
  const int col0 = blockIdx.y * 64;
  float acc[8][4] = {};
  for (int kt = 0; kt < DIN/16; ++kt) {
    float4 av[2];
#pragma unroll
    for (int r = 0; r < 2; ++r) {
      int idx = tid + 256*r;
      int m = idx >> 2, k4 = idx & 3;
      av[r] = *reinterpret_cast<const float4*>(
          &obs[(size_t)(row0+m)*DIN + kt*16 + k4*4]);
    }
    int bk = tid >> 4;
    int bc = (tid & 15) * 4;
    float4 bv = *reinterpret_cast<const float4*>(
        &Wemb[(size_t)(kt*16+bk)*DK + col0 + bc]);
    __syncthreads();
#pragma unroll
    for (int r = 0; r < 2; ++r) {
      int idx = tid + 256*r;
      int m = idx >> 2, k4 = idx & 3;
      As[k4*4+0][m] = av[r].x;
      As[k4*4+1][m] = av[r].y;
      As[k4*4+2][m] = av[r].z;
      As[k4*4+3][m] = av[r].w;
    }
    *reinterpret_cast<float4*>(&Bs[bk][bc]) = bv;
    __syncthreads();
#pragma unroll
    for (int k = 0; k < 16; ++k) {
      float4 a0 = *reinterpret_cast<const float4*>(&As[k][tr*8]);
      float4 a1 = *reinterpret_cast<const float4*>(&As[k][tr*8+4]);
      float4 b0 = *reinterpret_cast<const float4*>(&Bs[k][tc*4]);
      float ar[8] = {a0.x,a0.y,a0.z,a0.w,a1.x,a1.y,a1.z,a1.w};
      float br[4] = {b0.x,b0.y,b0.z,b0.w};
#pragma unroll
      for (int i = 0; i < 8; ++i)
#pragma unroll
        for (int j = 0; j < 4; ++j)
          acc[i][j] = fmaf(ar[i], br[j], acc[i][j]);
    }
  }
  float4 bias = *reinterpret_cast<const float4*>(&bemb[col0 + tc*4]);
#pragma unroll
  for (int i = 0; i < 8; ++i) {
    float4 o;
    o.x = acc[i][0] + bias.x; o.y = acc[i][1] + bias.y;
    o.z = acc[i][2] + bias.z; o.w = acc[i][3] + bias.w;
    *reinterpret_cast<float4*>(
        &x[(size_t)(row0 + tr*8 + i)*DK + col0 + tc*4]) = o;
  }
}

__global__ __launch_bounds__(256) void hg_gemm_scan(
    const float* __restrict__ x, const float* __restrict__ Whg,
    float* __restrict__ chP, float* __restrict__ chL)
{
  __shared__ float As[16][132];
  __shared__ float Bs[16][128];
  const int tid = threadIdx.x;
  const int tr = tid >> 4, tc = tid & 15;
  const int row0 = blockIdx.x * 128;
  const int col0 = blockIdx.y * 64;
  float acch[8][4] = {};
  float accg[8][4] = {};
  for (int kt = 0; kt < DK/16; ++kt) {
    float4 av[2];
#pragma unroll
    for (int r = 0; r < 2; ++r) {
      int idx = tid + 256*r;
      int m = idx >> 2, k4 = idx & 3;
      av[r] = *reinterpret_cast<const float4*>(
          &x[(size_t)(row0+m)*DK + kt*16 + k4*4]);
    }
    float4 bv[2];
#pragma unroll
    for (int r = 0; r < 2; ++r) {
      int idx = tid + 256*r;
      int k = idx >> 5;
      int c4 = idx & 31;
      int col = (c4 < 16) ? (col0 + c4*4) : (DIEXP + col0 + (c4-16)*4);
      bv[r] = *reinterpret_cast<const float4*>(
          &Whg[(size_t)(kt*16+k)*NHG + col]);
    }
    __syncthreads();
#pragma unroll
    for (int r = 0; r < 2; ++r) {
      int idx = tid + 256*r;
      int m = idx >> 2, k4 = idx & 3;
      As[k4*4+0][m] = av[r].x;
      As[k4*4+1][m] = av[r].y;
      As[k4*4+2][m] = av[r].z;
      As[k4*4+3][m] = av[r].w;
    }
#pragma unroll
    for (int r = 0; r < 2; ++r) {
      int idx = tid + 256*r;
      int k = idx >> 5;
      int c4 = idx & 31;
      int scol = (c4 < 16) ? c4*4 : (64 + (c4-16)*4);
      *reinterpret_cast<float4*>(&Bs[k][scol]) = bv[r];
    }
    __syncthreads();
#pragma unroll
    for (int k = 0; k < 16; ++k) {
      float4 a0 = *reinterpret_cast<const float4*>(&As[k][tr*8]);
      float4 a1 = *reinterpret_cast<const float4*>(&As[k][tr*8+4]);
      float4 bh = *reinterpret_cast<const float4*>(&Bs[k][tc*4]);
      float4 bg = *reinterpret_cast<const float4*>(&Bs[k][64 + tc*4]);
      float ar[8] = {a0.x,a0.y,a0.z,a0.w,a1.x,a1.y,a1.z,a1.w};
      float bhr[4] = {bh.x,bh.y,bh.z,bh.w};
      float bgr[4] = {bg.x,bg.y,bg.z,bg.w};
#pragma unroll
      for (int i = 0; i < 8; ++i) {
#pragma unroll
        for (int j = 0; j < 4; ++j) {
          acch[i][j] = fmaf(ar[i], bhr[j], acch[i][j]);
          accg[i][j] = fmaf(ar[i], bgr[j], accg[i][j]);
        }
      }
    }
  }
  float P[4], V[4];
#pragma unroll
  for (int j = 0; j < 4; ++j) { P[j] = 0.f; V[j] = -INFINITY; }
#pragma unroll
  for (int i = 0; i < 8; ++i) {
#pragma unroll
    for (int j = 0; j < 4; ++j) {
      float lcv, lvv;
      gate_math(accg[i][j], acch[i][j], lcv, lvv);
      V[j] = lax(lcv, V[j], lvv);
      P[j] += lcv;
    }
  }
  __syncthreads();
#pragma unroll
  for (int j = 0; j < 4; ++j) {
    As[tr][tc*4+j] = P[j];
    Bs[tr][tc*4+j] = V[j];
  }
  __syncthreads();
  if (tid < 64) {
    float Pa = 0.f, Va = -INFINITY;
#pragma unroll
    for (int t2 = 0; t2 < 16; ++t2) {
      float Pc = As[t2][tid], Vc = Bs[t2][tid];
      Va = lax(Pc, Va, Vc);
      Pa += Pc;
    }
    int b = row0 / SS;
    int c = (row0 % SS) / TCH;
    size_t o = ((size_t)(b*CCH + c))*DIEXP + col0 + tid;
    chP[o] = Pa;
    chL[o] = Va;
  }
}

// ---------------------------------------------------------------------------
// K3: combine chunk summaries (linear / log variants); K4: out = h @ W_out
// ---------------------------------------------------------------------------
__global__ __launch_bounds__(256) void combine_chunks(
    const float* __restrict__ chA, const float* __restrict__ chV,
    float* __restrict__ hl)
{
  int ch = blockIdx.x*256 + threadIdx.x;
  int b = ch / DIEXP, i = ch % DIEXP;
  float hv = 0.f;
#pragma unroll
  for (int c = 0; c < CCH; ++c) {
    size_t o = ((size_t)(b*CCH + c))*DIEXP + i;
    hv = fmaf(chA[o], hv, chV[o]);
  }
  hl[ch] = hv;
}

__global__ __launch_bounds__(256) void combine_chunks_log(
    const float* __restrict__ chP, const float* __restrict__ chL,
    float* __restrict__ hl)
{
  int ch = blockIdx.x*256 + threadIdx.x;
  int b = ch / DIEXP, i = ch % DIEXP;
  float L = -INFINITY;
#pragma unroll
  for (int c = 0; c < CCH; ++c) {
    size_t o = ((size_t)(b*CCH + c))*DIEXP + i;
    L = lax(chP[o], L, chL[o]);
  }
  hl[ch] = __expf(L);
}

__global__ __launch_bounds__(512) void out_gemm(
    const float* __restrict__ hl, const float* __restrict__ Wout,
    float* __restrict__ out)
{
  __shared__ float hs[DIEXP];
  int b = blockIdx.x;
  for (int i = threadIdx.x; i < DIEXP; i += 512) hs[i] = hl[b*DIEXP + i];
  __syncthreads();
  int d = threadIdx.x;
  float s = 0.f;
#pragma unroll 8
  for (int i = 0; i < DIEXP; ++i)
    s = fmaf(hs[i], Wout[(size_t)i*DK + d], s);
  out[(size_t)b*DK + d] = s;
}

// ---------------------------------------------------------------------------
extern "C" void kernel_launch(void* const* d_in, const int* in_sizes, int n_in,
                              void* d_out, int out_size, void* d_ws, size_t ws_size,
                              hipStream_t stream) {
  const float* obs  = (const float*)d_in[0];
  const float* Wemb = (const float*)d_in[1];
  const float* bemb = (const float*)d_in[2];
  const float* Whg  = (const float*)d_in[3];
  const float* Wout = (const float*)d_in[4];
  float* out = (float*)d_out;

  char* ws = (char*)d_ws;
  float* chA = (float*)ws;                                  // 1,572,864 B
  float* chV = (float*)(ws + 1572864);                      // 1,572,864 B
  float* hl  = (float*)(ws + 3145728);                      //    49,152 B
  // fp16 path:
  unsigned short* wt16   = (unsigned short*)(ws + 3194880); // 1,572,864 B
  unsigned short* wembT  = (unsigned short*)(ws + 4767744); //    65,536 B
  unsigned short* o16    = (unsigned short*)(ws + 4833280); // 8,388,608 B
  unsigned short* x16    = (unsigned short*)(ws + 13221888);// 67,108,864 B
  const size_t needNew = 80330752;
  // fallback:
  float* xf = (float*)(ws + 3194880);                       // 134,217,728 B
  const size_t needOld = 137412608;

  if (ws_size >= needNew) {
    obs2h<<<dim3(MROWS*DIN/1024), 256, 0, stream>>>(obs, o16);
    wembT16<<<dim3(DK), 64, 0, stream>>>(Wemb, wembT);
    wsplit16<<<dim3(NHG), 256, 0, stream>>>(Whg, wt16);
    emb_mfma<<<dim3(MROWS/128, DK/256), 256, 0, stream>>>(o16, wembT, bemb, x16);
    hg_mfma_scan<<<dim3(MROWS/128, DIEXP/128), 256, 0, stream>>>(
        x16, wt16, chA, chV);
    combine_chunks<<<dim3(NCHAN/256), 256, 0, stream>>>(chA, chV, hl);
  } else if (ws_size >= needOld) {
    emb_gemm<<<dim3(MROWS/128, DK/64), 256, 0, stream>>>(obs, Wemb, bemb, xf);
    hg_gemm_scan<<<dim3(MROWS/128, DIEXP/64), 256, 0, stream>>>(xf, Whg, chA, chV);
    combine_chunks_log<<<dim3(NCHAN/256), 256, 0, stream>>>(chA, chV, hl);
  }
  out_gemm<<<dim3(NB), 512, 0, stream>>>(hl, Wout, out);
}

// Round 7
// 206.280 us; speedup vs baseline: 6.8334x; 1.0136x over previous
//
#include <hip/hip_runtime.h>
#include <cstdint>
#include <cstddef>
#include <math.h>

// Problem dims
#define NB    16
#define SS    4096
#define DIN   64
#define DK    512
#define DIEXP 768
#define MROWS (NB*SS)      // 65536
#define NHG   (2*DIEXP)    // 1536
#define CCH   32           // chunks per sequence (chunk len 128)
#define TCH   128
#define NCHAN (NB*DIEXP)   // 12288

typedef __attribute__((ext_vector_type(8))) _Float16 half8;  // 8 fp16 (4 VGPRs)
typedef __attribute__((ext_vector_type(4))) float f32x4;

#define GL2LDS16(g, lp) \
  __builtin_amdgcn_global_load_lds( \
      (const __attribute__((address_space(1))) void*)(g), \
      (__attribute__((address_space(3))) void*)(lp), 16, 0, 0)

__device__ __forceinline__ unsigned short f2h(float f) {
  _Float16 h = (_Float16)f;            // v_cvt_f16_f32, RNE
  return __builtin_bit_cast(unsigned short, h);
}

// log-space helpers (fallback path only)
__device__ __forceinline__ float lax(float P, float L, float V) {
  float xx = P + L;
  float m  = fmaxf(xx, V);
  float d  = fminf(xx, V) - m;
  return m + __logf(1.f + __expf(d));
}
__device__ __forceinline__ void gate_math(float g, float h, float& lcv, float& lvv) {
  float spg  = fmaxf(g, 0.f) + __logf(1.f + __expf(-fabsf(g)));
  float logg = (h >= 0.f) ? __logf(h + 0.5f)
                          : (h - __logf(1.f + __expf(h)));
  lcv = -spg;
  lvv = g - spg + logg;
}

// ---------------------------------------------------------------------------
// Pre-kernels: obs -> fp16; merged weight prep (Whg^T fp16 + Wemb^T fp16)
// ---------------------------------------------------------------------------
__global__ __launch_bounds__(256) void obs2h(
    const float* __restrict__ obs, unsigned short* __restrict__ o16)
{
  size_t i = ((size_t)blockIdx.x*256 + threadIdx.x)*4;   // MROWS*DIN total
  float4 v = *reinterpret_cast<const float4*>(&obs[i]);
  ushort4 o;
  o.x = f2h(v.x); o.y = f2h(v.y); o.z = f2h(v.z); o.w = f2h(v.w);
  *reinterpret_cast<ushort4*>(&o16[i]) = o;
}

__global__ __launch_bounds__(256) void wprep(
    const float* __restrict__ Whg, const float* __restrict__ Wemb,
    unsigned short* __restrict__ wt16, unsigned short* __restrict__ wembT)
{
  int bid = blockIdx.x;
  if (bid < NHG) {
    int j = bid;
    for (int k = threadIdx.x; k < DK; k += 256)
      wt16[(size_t)j*DK + k] = f2h(Whg[(size_t)k*NHG + j]);
  } else {
    int n = (bid - NHG)*4 + (threadIdx.x >> 6);   // 0..511
    int k = threadIdx.x & 63;
    wembT[n*DIN + k] = f2h(Wemb[(size_t)k*DK + n]);
  }
}

// ---------------------------------------------------------------------------
// K1: x16 = fp16(obs @ W_emb + b_emb). Single-shot K=64 MFMA tile.
// Epilogue via LDS bounce -> coalesced 16B stores.
// ---------------------------------------------------------------------------
__global__ __launch_bounds__(256, 2) void emb_mfma(
    const unsigned short* __restrict__ o16, const unsigned short* __restrict__ wembT,
    const float* __restrict__ bemb, unsigned short* __restrict__ x16)
{
  __shared__ char smem[49152];
  const int t = threadIdx.x;
  const int row0 = blockIdx.x * 128;
  const int col0 = blockIdx.y * 256;
  const int w = t >> 6, l = t & 63;

#pragma unroll
  for (int q = 0; q < 12; ++q) {
    int i = w*12 + q;
    int s = l & 3;
    const unsigned short* src;
    if (i < 16) {
      int kk = i >> 3, ii = i & 7;
      int r = ii*16 + (l >> 2);
      int slog = s ^ ((r >> 1) & 3);
      src = o16 + (size_t)(row0 + r)*DIN + kk*32 + slog*8;
    } else {
      int kk = (i - 16) >> 4, ii = (i - 16) & 15;
      int c = ii*16 + (l >> 2);
      int slog = s ^ ((c >> 1) & 3);
      src = wembT + (size_t)(col0 + c)*DIN + kk*32 + slog*8;
    }
    GL2LDS16(src, smem + i*1024);
  }
  __syncthreads();

  const int u  = l & 15;
  const int qh = l >> 4;
  const int phys = qh ^ ((u >> 1) & 3);
  const int aoff = u*64 + phys*16;
  const int boff = 16384 + (w*64 + u)*64 + phys*16;

  f32x4 acc[8][4];
#pragma unroll
  for (int m = 0; m < 8; ++m)
#pragma unroll
    for (int n = 0; n < 4; ++n)
      acc[m][n] = (f32x4){0.f, 0.f, 0.f, 0.f};

#pragma unroll
  for (int kk = 0; kk < 2; ++kk) {
    half8 b[4];
#pragma unroll
    for (int n = 0; n < 4; ++n)
      b[n] = *reinterpret_cast<const half8*>(smem + kk*16384 + boff + n*1024);
#pragma unroll
    for (int m = 0; m < 8; ++m) {
      half8 a = *reinterpret_cast<const half8*>(smem + kk*8192 + aoff + m*1024);
#pragma unroll
      for (int n = 0; n < 4; ++n)
        acc[m][n] = __builtin_amdgcn_mfma_f32_16x16x32_f16(a, b[n], acc[m][n], 0, 0, 0);
    }
  }

  float bias[4];
#pragma unroll
  for (int n = 0; n < 4; ++n) bias[n] = bemb[col0 + w*64 + n*16 + u];

  // LDS-bounce epilogue: 2 half-passes of 128 cols each -> coalesced stores
  __syncthreads();                 // staging data no longer needed
  unsigned short* lbuf = reinterpret_cast<unsigned short*>(smem);  // [128][136]
#pragma unroll
  for (int half = 0; half < 2; ++half) {
#pragma unroll
    for (int m = 0; m < 8; ++m)
#pragma unroll
      for (int np = 0; np < 2; ++np) {
        int n = 2*half + np;
        int c = w*32 + np*16 + u;             // 0..127 within half
#pragma unroll
        for (int r = 0; r < 4; ++r) {
          int row = m*16 + qh*4 + r;
          lbuf[row*136 + c] = f2h(acc[m][n][r] + bias[n]);
        }
      }
    __syncthreads();
#pragma unroll
    for (int it = 0; it < 8; ++it) {
      int idx = t + 256*it;                    // 0..2047
      int row = idx >> 4;                      // 0..127
      int c16 = idx & 15;                      // chunk of 8 cols
      uint4 v = *reinterpret_cast<const uint4*>(&lbuf[row*136 + c16*8]);
      int gc = col0 + (c16 >> 2)*64 + half*32 + (c16 & 3)*8;
      *reinterpret_cast<uint4*>(&x16[(size_t)(row0+row)*DK + gc]) = v;
    }
    __syncthreads();
  }
}

// ---------------------------------------------------------------------------
// K2: fp16 MFMA GEMM + fused LINEAR-space gate math + 128-step chunk scan.
// 3-buffer pipeline, counted vmcnt(12). Grid TRANSPOSED: (6 col-blocks, 512
// row-blocks) so the 6 blocks sharing an A-panel are dispatch-adjacent and
// the panel is HBM-fetched once (L2/L3 hits for the rest).
// ---------------------------------------------------------------------------
__global__ __launch_bounds__(256, 2) void hg_mfma_scan(
    const unsigned short* __restrict__ x16, const unsigned short* __restrict__ wt16,
    float* __restrict__ chA, float* __restrict__ chV)
{
  __shared__ char smem[73728];            // 3 x 24 KB buffers
  const int t = threadIdx.x;
  const int row0 = blockIdx.y * 128;
  const int colbase = blockIdx.x * 128;   // channel base (128 channels/block)
  const int w = t >> 6, l = t & 63;

  // per-wave 6 staging chunks: i 0..7 = A rows, 8..23 = B cols (24 x 1KB)
  const unsigned short* srcp[6];
  int ldst[6];
#pragma unroll
  for (int q = 0; q < 6; ++q) {
    int i = w*6 + q;
    int s = l & 3;
    if (i < 8) {
      int r = i*16 + (l >> 2);
      int slog = s ^ ((r >> 1) & 3);
      srcp[q] = x16 + (size_t)(row0 + r)*DK + slog*8;
    } else {
      int c = (i - 8)*16 + (l >> 2);
      int slog = s ^ ((c >> 1) & 3);
      int grp = c >> 4, uu = c & 15;
      int wr = ((grp & 1) ? DIEXP : 0) + colbase + (grp >> 1)*16 + uu;
      srcp[q] = wt16 + (size_t)wr*DK + slog*8;
    }
    ldst[q] = i*1024;
  }

  // fragment read maps (proven layout; B region at +8192 within a buffer)
  const int u  = l & 15;
  const int qh = l >> 4;
  const int phys = qh ^ ((u >> 1) & 3);
  const int aoff = u*64 + phys*16;                   // + m*1024 + buf
  const int boff = 8192 + (w*64 + u)*64 + phys*16;   // + n*1024 + buf

  f32x4 acc[8][4];
#pragma unroll
  for (int m = 0; m < 8; ++m)
#pragma unroll
    for (int n = 0; n < 4; ++n)
      acc[m][n] = (f32x4){0.f, 0.f, 0.f, 0.f};

  // prologue: stage tiles 0 and 1
#pragma unroll
  for (int q = 0; q < 6; ++q) GL2LDS16(srcp[q],      smem +     0 + ldst[q]);
#pragma unroll
  for (int q = 0; q < 6; ++q) GL2LDS16(srcp[q] + 32, smem + 24576 + ldst[q]);
  int off_p = 49152, off_c = 0, off_n = 24576;   // p=free, c=tile kt, n=tile kt+1

#pragma unroll 1
  for (int kt = 0; kt < DK/32; ++kt) {
    asm volatile("s_waitcnt lgkmcnt(0)" ::: "memory");  // prev ds_reads retired
    __builtin_amdgcn_s_barrier();                       // off_p free everywhere
    if (kt < DK/32 - 2) {
#pragma unroll
      for (int q = 0; q < 6; ++q)
        GL2LDS16(srcp[q] + (kt + 2)*32, smem + off_p + ldst[q]);
      asm volatile("s_waitcnt vmcnt(12)" ::: "memory"); // tile kt landed
    } else if (kt == DK/32 - 2) {
      asm volatile("s_waitcnt vmcnt(6)" ::: "memory");
    } else {
      asm volatile("s_waitcnt vmcnt(0)" ::: "memory");
    }
    __builtin_amdgcn_s_barrier();                       // tile kt visible
    __builtin_amdgcn_sched_barrier(0);
    const char* bb = smem + off_c;
    half8 b[4];
#pragma unroll
    for (int n = 0; n < 4; ++n)
      b[n] = *reinterpret_cast<const half8*>(bb + boff + n*1024);
    __builtin_amdgcn_s_setprio(1);
#pragma unroll
    for (int m = 0; m < 8; ++m) {
      half8 a = *reinterpret_cast<const half8*>(bb + aoff + m*1024);
#pragma unroll
      for (int n = 0; n < 4; ++n)
        acc[m][n] = __builtin_amdgcn_mfma_f32_16x16x32_f16(a, b[n], acc[m][n], 0, 0, 0);
    }
    __builtin_amdgcn_s_setprio(0);
    int t0 = off_p; off_p = off_c; off_c = off_n; off_n = t0;
  }
  __syncthreads();              // loop fully done; overlay scratch on smem

  // ---- fused linear gate math + chunk scan (wave: 128 rows x 32 channels) ----
  float* segA = reinterpret_cast<float*>(smem);            // 16 KB
  float* segV = reinterpret_cast<float*>(smem + 16384);    // 16 KB
  // C/D layout: col = lane&15, row = (lane>>4)*4 + reg -> 4 consecutive
  // timesteps per lane; per-lane 4-step segment summary (A, V).
#pragma unroll
  for (int p = 0; p < 2; ++p) {        // channel pair (n=2p: hidden, 2p+1: gate)
#pragma unroll
    for (int m = 0; m < 8; ++m) {
      float A = 1.f, V = 0.f;
#pragma unroll
      for (int r = 0; r < 4; ++r) {
        float g = acc[m][2*p+1][r];
        float h = acc[m][2*p][r];
        float a  = __builtin_amdgcn_rcpf(1.f + __expf(g));    // sigmoid(-g) = 1-z
        float z  = 1.f - a;                                   // sigmoid(g)
        float sh = __builtin_amdgcn_rcpf(1.f + __expf(-h));   // sigmoid(h)
        float gv = (h >= 0.f) ? (h + 0.5f) : sh;              // g(h~)
        V = fmaf(a, V, z * gv);
        A *= a;
      }
      int sidx = w*1024 + ((m*4 + qh)*2 + p)*16 + u;
      segA[sidx] = A;
      segV[sidx] = V;
    }
  }
  __syncthreads();
  if (l < 32) {                        // 32 channels per wave
    int p = l >> 4, uu = l & 15;
    float Aa = 1.f, Va = 0.f;
#pragma unroll
    for (int mm = 0; mm < 8; ++mm)     // time order: m major, qh minor
#pragma unroll
      for (int hh = 0; hh < 4; ++hh) {
        int sidx = w*1024 + ((mm*4 + hh)*2 + p)*16 + uu;
        float As = segA[sidx], Vs = segV[sidx];
        Va = fmaf(As, Va, Vs);
        Aa *= As;
      }
    int b = row0 >> 12;                // row0 / 4096
    int c = (row0 & 4095) >> 7;        // chunk within sequence
    int j = colbase + 32*w + p*16 + uu;
    size_t o = ((size_t)(b*CCH + c))*DIEXP + j;
    chA[o] = Aa;
    chV[o] = Va;
  }
}

// ---------------------------------------------------------------------------
// K3 (fused tail): combine chunk summaries + out = h_last @ W_out
// ---------------------------------------------------------------------------
__global__ __launch_bounds__(512) void combine_out(
    const float* __restrict__ chA, const float* __restrict__ chV,
    const float* __restrict__ Wout, float* __restrict__ out)
{
  __shared__ float hs[DIEXP];
  int b = blockIdx.x;
  int t = threadIdx.x;
  for (int ch = t; ch < DIEXP; ch += 512) {
    float hv = 0.f;
#pragma unroll
    for (int c = 0; c < CCH; ++c) {
      size_t o = ((size_t)(b*CCH + c))*DIEXP + ch;
      hv = fmaf(chA[o], hv, chV[o]);
    }
    hs[ch] = hv;
  }
  __syncthreads();
  int d = t;
  float s = 0.f;
#pragma unroll 8
  for (int i = 0; i < DIEXP; ++i)
    s = fmaf(hs[i], Wout[(size_t)i*DK + d], s);
  out[(size_t)b*DK + d] = s;
}

// ---------------------------------------------------------------------------
// Fallback path (round-2, proven): fp32 x + VALU GEMM + log-space scan
// ---------------------------------------------------------------------------
__global__ __launch_bounds__(256) void emb_gemm(
    const float* __restrict__ obs, const float* __restrict__ Wemb,
    const float* __restrict__ bemb, float* __restrict__ x)
{
  __shared__ float As[16][132];
  __shared__ float Bs[16][64];
  const int tid = threadIdx.x;
  const int tr = tid >> 4, tc = tid & 15;
  const int row0 = blockIdx.x * 128;
  const int col0 = blockIdx.y * 64;
  float acc[8][4] = {};
  for (int kt = 0; kt < DIN/16; ++kt) {
    float4 av[2];
#pragma unroll
    for (int r = 0; r < 2; ++r) {
      int idx = tid + 256*r;
      int m = idx >> 2, k4 = idx & 3;
      av[r] = *reinterpret_cast<const float4*>(
          &obs[(size_t)(row0+m)*DIN + kt*16 + k4*4]);
    }
    int bk = tid >> 4;
    int bc = (tid & 15) * 4;
    float4 bv = *reinterpret_cast<const float4*>(
        &Wemb[(size_t)(kt*16+bk)*DK + col0 + bc]);
    __syncthreads();
#pragma unroll
    for (int r = 0; r < 2; ++r) {
      int idx = tid + 256*r;
      int m = idx >> 2, k4 = idx & 3;
      As[k4*4+0][m] = av[r].x;
      As[k4*4+1][m] = av[r].y;
      As[k4*4+2][m] = av[r].z;
      As[k4*4+3][m] = av[r].w;
    }
    *reinterpret_cast<float4*>(&Bs[bk][bc]) = bv;
    __syncthreads();
#pragma unroll
    for (int k = 0; k < 16; ++k) {
      float4 a0 = *reinterpret_cast<const float4*>(&As[k][tr*8]);
      float4 a1 = *reinterpret_cast<const float4*>(&As[k][tr*8+4]);
      float4 b0 = *reinterpret_cast<const float4*>(&Bs[k][tc*4]);
      float ar[8] = {a0.x,a0.y,a0.z,a0.w,a1.x,a1.y,a1.z,a1.w};
      float br[4] = {b0.x,b0.y,b0.z,b0.w};
#pragma unroll
      for (int i = 0; i < 8; ++i)
#pragma unroll
        for (int j = 0; j < 4; ++j)
          acc[i][j] = fmaf(ar[i], br[j], acc[i][j]);
    }
  }
  float4 bias = *reinterpret_cast<const float4*>(&bemb[col0 + tc*4]);
#pragma unroll
  for (int i = 0; i < 8; ++i) {
    float4 o;
    o.x = acc[i][0] + bias.x; o.y = acc[i][1] + bias.y;
    o.z = acc[i][2] + bias.z; o.w = acc[i][3] + bias.w;
    *reinterpret_cast<float4*>(
        &x[(size_t)(row0 + tr*8 + i)*DK + col0 + tc*4]) = o;
  }
}

__global__ __launch_bounds__(256) void hg_gemm_scan(
    const float* __restrict__ x, const float* __restrict__ Whg,
    float* __restrict__ chP, float* __restrict__ chL)
{
  __shared__ float As[16][132];
  __shared__ float Bs[16][128];
  const int tid = threadIdx.x;
  const int tr = tid >> 4, tc = tid & 15;
  const int row0 = blockIdx.x * 128;
  const int col0 = blockIdx.y * 64;
  float acch[8][4] = {};
  float accg[8][4] = {};
  for (int kt = 0; kt < DK/16; ++kt) {
    float4 av[2];
#pragma unroll
    for (int r = 0; r < 2; ++r) {
      int idx = tid + 256*r;
      int m = idx >> 2, k4 = idx & 3;
      av[r] = *reinterpret_cast<const float4*>(
          &x[(size_t)(row0+m)*DK + kt*16 + k4*4]);
    }
    float4 bv[2];
#pragma unroll
    for (int r = 0; r < 2; ++r) {
      int idx = tid + 256*r;
      int k = idx >> 5;
      int c4 = idx & 31;
      int col = (c4 < 16) ? (col0 + c4*4) : (DIEXP + col0 + (c4-16)*4);
      bv[r] = *reinterpret_cast<const float4*>(
          &Whg[(size_t)(kt*16+k)*NHG + col]);
    }
    __syncthreads();
#pragma unroll
    for (int r = 0; r < 2; ++r) {
      int idx = tid + 256*r;
      int m = idx >> 2, k4 = idx & 3;
      As[k4*4+0][m] = av[r].x;
      As[k4*4+1][m] = av[r].y;
      As[k4*4+2][m] = av[r].z;
      As[k4*4+3][m] = av[r].w;
    }
#pragma unroll
    for (int r = 0; r < 2; ++r) {
      int idx = tid + 256*r;
      int k = idx >> 5;
      int c4 = idx & 31;
      int scol = (c4 < 16) ? c4*4 : (64 + (c4-16)*4);
      *reinterpret_cast<float4*>(&Bs[k][scol]) = bv[r];
    }
    __syncthreads();
#pragma unroll
    for (int k = 0; k < 16; ++k) {
      float4 a0 = *reinterpret_cast<const float4*>(&As[k][tr*8]);
      float4 a1 = *reinterpret_cast<const float4*>(&As[k][tr*8+4]);
      float4 bh = *reinterpret_cast<const float4*>(&Bs[k][tc*4]);
      float4 bg = *reinterpret_cast<const float4*>(&Bs[k][64 + tc*4]);
      float ar[8] = {a0.x,a0.y,a0.z,a0.w,a1.x,a1.y,a1.z,a1.w};
      float bhr[4] = {bh.x,bh.y,bh.z,bh.w};
      float bgr[4] = {bg.x,bg.y,bg.z,bg.w};
#pragma unroll
      for (int i = 0; i < 8; ++i) {
#pragma unroll
        for (int j = 0; j < 4; ++j) {
          acch[i][j] = fmaf(ar[i], bhr[j], acch[i][j]);
          accg[i][j] = fmaf(ar[i], bgr[j], accg[i][j]);
        }
      }
    }
  }
  float P[4], V[4];
#pragma unroll
  for (int j = 0; j < 4; ++j) { P[j] = 0.f; V[j] = -INFINITY; }
#pragma unroll
  for (int i = 0; i < 8; ++i) {
#pragma unroll
    for (int j = 0; j < 4; ++j) {
      float lcv, lvv;
      gate_math(accg[i][j], acch[i][j], lcv, lvv);
      V[j] = lax(lcv, V[j], lvv);
      P[j] += lcv;
    }
  }
  __syncthreads();
#pragma unroll
  for (int j = 0; j < 4; ++j) {
    As[tr][tc*4+j] = P[j];
    Bs[tr][tc*4+j] = V[j];
  }
  __syncthreads();
  if (tid < 64) {
    float Pa = 0.f, Va = -INFINITY;
#pragma unroll
    for (int t2 = 0; t2 < 16; ++t2) {
      float Pc = As[t2][tid], Vc = Bs[t2][tid];
      Va = lax(Pc, Va, Vc);
      Pa += Pc;
    }
    int b = row0 / SS;
    int c = (row0 % SS) / TCH;
    size_t o = ((size_t)(b*CCH + c))*DIEXP + col0 + tid;
    chP[o] = Pa;
    chL[o] = Va;
  }
}

__global__ __launch_bounds__(256) void combine_chunks_log(
    const float* __restrict__ chP, const float* __restrict__ chL,
    float* __restrict__ hl)
{
  int ch = blockIdx.x*256 + threadIdx.x;
  int b = ch / DIEXP, i = ch % DIEXP;
  float L = -INFINITY;
#pragma unroll
  for (int c = 0; c < CCH; ++c) {
    size_t o = ((size_t)(b*CCH + c))*DIEXP + i;
    L = lax(chP[o], L, chL[o]);
  }
  hl[ch] = __expf(L);
}

__global__ __launch_bounds__(512) void out_gemm(
    const float* __restrict__ hl, const float* __restrict__ Wout,
    float* __restrict__ out)
{
  __shared__ float hs[DIEXP];
  int b = blockIdx.x;
  for (int i = threadIdx.x; i < DIEXP; i += 512) hs[i] = hl[b*DIEXP + i];
  __syncthreads();
  int d = threadIdx.x;
  float s = 0.f;
#pragma unroll 8
  for (int i = 0; i < DIEXP; ++i)
    s = fmaf(hs[i], Wout[(size_t)i*DK + d], s);
  out[(size_t)b*DK + d] = s;
}

// ---------------------------------------------------------------------------
extern "C" void kernel_launch(void* const* d_in, const int* in_sizes, int n_in,
                              void* d_out, int out_size, void* d_ws, size_t ws_size,
                              hipStream_t stream) {
  const float* obs  = (const float*)d_in[0];
  const float* Wemb = (const float*)d_in[1];
  const float* bemb = (const float*)d_in[2];
  const float* Whg  = (const float*)d_in[3];
  const float* Wout = (const float*)d_in[4];
  float* out = (float*)d_out;

  char* ws = (char*)d_ws;
  float* chA = (float*)ws;                                  // 1,572,864 B
  float* chV = (float*)(ws + 1572864);                      // 1,572,864 B
  float* hl  = (float*)(ws + 3145728);                      //    49,152 B
  // fp16 path:
  unsigned short* wt16   = (unsigned short*)(ws + 3194880); // 1,572,864 B
  unsigned short* wembT  = (unsigned short*)(ws + 4767744); //    65,536 B
  unsigned short* o16    = (unsigned short*)(ws + 4833280); // 8,388,608 B
  unsigned short* x16    = (unsigned short*)(ws + 13221888);// 67,108,864 B
  const size_t needNew = 80330752;
  // fallback:
  float* xf = (float*)(ws + 3194880);                       // 134,217,728 B
  const size_t needOld = 137412608;

  if (ws_size >= needNew) {
    obs2h<<<dim3(MROWS*DIN/1024), 256, 0, stream>>>(obs, o16);
    wprep<<<dim3(NHG + DK/4), 256, 0, stream>>>(Whg, Wemb, wt16, wembT);
    emb_mfma<<<dim3(MROWS/128, DK/256), 256, 0, stream>>>(o16, wembT, bemb, x16);
    hg_mfma_scan<<<dim3(DIEXP/128, MROWS/128), 256, 0, stream>>>(
        x16, wt16, chA, chV);
    combine_out<<<dim3(NB), 512, 0, stream>>>(chA, chV, Wout, out);
  } else if (ws_size >= needOld) {
    emb_gemm<<<dim3(MROWS/128, DK/64), 256, 0, stream>>>(obs, Wemb, bemb, xf);
    hg_gemm_scan<<<dim3(MROWS/128, DIEXP/64), 256, 0, stream>>>(xf, Whg, chA, chV);
    combine_chunks_log<<<dim3(NCHAN/256), 256, 0, stream>>>(chA, chV, hl);
    out_gemm<<<dim3(NB), 512, 0, stream>>>(hl, Wout, out);
  }
}